// Round 5
// baseline (652.528 us; speedup 1.0000x reference)
//
#include <hip/hip_runtime.h>
#include <hip/hip_bf16.h>
#include <math.h>

typedef __attribute__((ext_vector_type(4))) float f32x4;
typedef __attribute__((ext_vector_type(8))) short s16x8;
typedef __hip_bfloat16 bf16;

#define MB (1024ull*1024ull)
// workspace layout (bytes) — total 17 MB
#define GATE_OFF    (0ull)          // 1024*4 f32 = 16KB
#define ACTW_OFF    (16ull*1024)    // 9 f32
#define U_OFF       (20ull*1024)    // 2048 f32
#define CMEAN_OFF   (28ull*1024)    // 1024 f32
#define PART_OFF    (64ull*1024)    // 8*3072 f32 = 96KB (col-mean partials)
#define HIDDEN_OFF  (1ull*MB)       // bf16 1024x2048 (4MB)
#define RATT_OFF    (5ull*MB)       // bf16 1024x2048 (4MB) logits -> softmax in-place
#define CAND_OFF    (9ull*MB)       // bf16 1024x1024 (2MB)
#define PREDS_OFF   (11ull*MB)      // f32 1024x512  (2MB)
#define READ_OFF    (13ull*MB)      // f32 1024x1024 (4MB) -> ends 17MB

__device__ __forceinline__ short f2bf_s(float f) {
    bf16 h = __float2bfloat16(f);
    return *reinterpret_cast<short*>(&h);
}

__device__ __forceinline__ float qact(float x, const float* w) {
    float ex  = __expf(x);
    float sig = 1.f / (1.f + __expf(-x));
    float elu = x > 0.f ? x : ex - 1.f;
    float th  = tanhf(x);
    float rel = fmaxf(x, 0.f);
    float silu = x * sig;
    float gel = 0.5f * x * (1.f + erff(x * 0.70710678118654752f));
    float sel = 1.0507009873554805f * (x > 0.f ? x : 1.6732632423543772f * (ex - 1.f));
    float sp  = (x > 15.f) ? x : log1pf(ex);
    float mish = x * tanhf(sp);
    return w[0]*sig + w[1]*elu + w[2]*th + w[3]*rel + w[4]*silu
         + w[5]*gel + w[6]*sel + w[7]*mish + w[8]*x;
}

// ---------------- gate softmax + act-weight softmax (all f32) ----------------
__global__ __launch_bounds__(256) void k_gate(const float* __restrict__ x,
                                              const float* __restrict__ gw,
                                              const float* __restrict__ gb,
                                              const float* __restrict__ aw_in,
                                              float* __restrict__ gate,
                                              float* __restrict__ actw) {
    int b = blockIdx.x, t = threadIdx.x, w = t >> 6, lane = t & 63;
    __shared__ float l[4];
    float s = 0.f;
    for (int k = lane; k < 1024; k += 64)
        s += x[(size_t)b*1024 + k] * gw[k*4 + w];
    #pragma unroll
    for (int off = 32; off; off >>= 1) s += __shfl_xor(s, off);
    if (lane == 0) l[w] = s + gb[w];
    __syncthreads();
    if (t == 0) {
        float m = fmaxf(fmaxf(l[0], l[1]), fmaxf(l[2], l[3]));
        float e0 = __expf(l[0]-m), e1 = __expf(l[1]-m), e2 = __expf(l[2]-m), e3 = __expf(l[3]-m);
        float inv = 1.f / (e0+e1+e2+e3);
        gate[b*4+0] = e0*inv; gate[b*4+1] = e1*inv;
        gate[b*4+2] = e2*inv; gate[b*4+3] = e3*inv;
    }
    if (b == 0 && t == 64) {
        float a[9]; float m = -1e30f;
        for (int i = 0; i < 9; i++) { a[i] = aw_in[i]; m = fmaxf(m, a[i]); }
        float ss = 0.f;
        for (int i = 0; i < 9; i++) { a[i] = __expf(a[i]-m); ss += a[i]; }
        float inv = 1.f / ss;
        for (int i = 0; i < 9; i++) actw[i] = a[i]*inv;
    }
}

// ---------------- GEMM (NN): C(MxN) = A(MxK) @ B(KxN), 128x128 tile, BK=32 ----------------
// (HW-validated round 4 — unchanged)
template <int MODE, int AF32>
__global__ __launch_bounds__(256, 2) void gemm_nn(
        const void* __restrict__ Av, const float* __restrict__ B,
        int K, int ldb,
        const float* __restrict__ bias,
        float* __restrict__ outF, bf16* __restrict__ outH,
        const float* __restrict__ gate, const float* __restrict__ actw,
        const float* __restrict__ mask, int outStride) {
    __shared__ __align__(16) short sA[128*32];
    __shared__ __align__(16) short sB[128*32];
    int t = threadIdx.x, lane = t & 63;
    int rowBase = blockIdx.y * 128, colBase = blockIdx.x * 128;
    int lm = lane & 15, lq = lane >> 4;
    int w = t >> 6;
    int qm = (w >> 1) * 64, qn = (w & 1) * 64;

    f32x4 acc[4][4];
    #pragma unroll
    for (int i = 0; i < 4; i++)
        #pragma unroll
        for (int j = 0; j < 4; j++) acc[i][j] = (f32x4){0.f, 0.f, 0.f, 0.f};

    int ar = t >> 2, ak = (t & 3) * 8;
    int bk = t >> 3, bn0 = (t & 7) * 16;
    int swz = (((t >> 6) ^ (t & 3)) << 3) | (bk & 7);

    for (int k0 = 0; k0 < K; k0 += 32) {
        __syncthreads();
        if (AF32) {
            const float* Af = (const float*)Av;
            #pragma unroll
            for (int h = 0; h < 2; h++) {
                int r = ar + h*64;
                const float* src = Af + (size_t)(rowBase + r)*K + k0 + ak;
                s16x8 av;
                #pragma unroll
                for (int j = 0; j < 8; j++) av[j] = f2bf_s(src[j]);
                *reinterpret_cast<s16x8*>(sA + r*32 + ak) = av;
            }
        } else {
            const bf16* Ab = (const bf16*)Av;
            *reinterpret_cast<s16x8*>(sA + ar*32 + ak) =
                *reinterpret_cast<const s16x8*>(Ab + (size_t)(rowBase + ar)*K + k0 + ak);
            *reinterpret_cast<s16x8*>(sA + (ar + 64)*32 + ak) =
                *reinterpret_cast<const s16x8*>(Ab + (size_t)(rowBase + ar + 64)*K + k0 + ak);
        }
        const float* bsrc = B + (size_t)(k0 + bk)*ldb + colBase + bn0;
        #pragma unroll
        for (int j = 0; j < 16; j++)
            sB[(bn0 + j)*32 + swz] = f2bf_s(bsrc[j]);
        __syncthreads();
        s16x8 af[4], bfr[4];
        #pragma unroll
        for (int mi = 0; mi < 4; mi++)
            af[mi] = *reinterpret_cast<const s16x8*>(sA + (qm + mi*16 + lm)*32 + lq*8);
        #pragma unroll
        for (int ni = 0; ni < 4; ni++) {
            int n = qn + ni*16 + lm;
            bfr[ni] = *reinterpret_cast<const s16x8*>(sB + n*32 + ((lq ^ ni) << 3));
        }
        #pragma unroll
        for (int mi = 0; mi < 4; mi++)
            #pragma unroll
            for (int ni = 0; ni < 4; ni++)
                acc[mi][ni] = __builtin_amdgcn_mfma_f32_16x16x32_bf16(af[mi], bfr[ni], acc[mi][ni], 0, 0, 0);
    }

    if (MODE == 4) {
        float aw[9];
        #pragma unroll
        for (int i = 0; i < 9; i++) aw[i] = actw[i];
        #pragma unroll
        for (int mi = 0; mi < 4; mi++) {
            int row0 = rowBase + qm + mi*16 + lq*4;
            #pragma unroll
            for (int ni = 0; ni < 4; ni++) {
                int col = colBase + qn + ni*16 + lm;
                int n = col & 3;
                float bb = bias[col];
                f32x4 v = acc[mi][ni];
                #pragma unroll
                for (int r = 0; r < 4; r++) v[r] = (v[r] + bb) * gate[(row0 + r)*4 + n];
                #pragma unroll
                for (int r = 0; r < 4; r++) v[r] += __shfl_xor(v[r], 1);
                #pragma unroll
                for (int r = 0; r < 4; r++) v[r] += __shfl_xor(v[r], 2);
                if ((lane & 3) == 0) {
                    int uu = col >> 2;
                    float mk = mask[uu];
                    #pragma unroll
                    for (int r = 0; r < 4; r++)
                        outH[(size_t)(row0 + r)*outStride + uu] = __float2bfloat16(qact(v[r], aw) * mk);
                }
            }
        }
    } else {
        #pragma unroll
        for (int mi = 0; mi < 4; mi++) {
            int row0 = rowBase + qm + mi*16 + lq*4;
            #pragma unroll
            for (int ni = 0; ni < 4; ni++) {
                int col = colBase + qn + ni*16 + lm;
                float bb = (MODE == 3) ? 0.f : bias[col];
                #pragma unroll
                for (int r = 0; r < 4; r++) {
                    float vv = acc[mi][ni][r] + bb;
                    size_t oi = (size_t)(row0 + r)*outStride + col;
                    if (MODE == 0) outH[oi] = __float2bfloat16(vv);
                    if (MODE == 1) outH[oi] = __float2bfloat16(tanhf(vv));
                    if (MODE == 2 || MODE == 3) outF[oi] = vv;
                }
            }
        }
    }
}

// ---------------- in-place row softmax over 2048 cols (bf16 buffer) ----------------
__global__ __launch_bounds__(256) void k_softmax(bf16* __restrict__ ratt) {
    int b = blockIdx.x, t = threadIdx.x, w = t >> 6, lane = t & 63;
    __shared__ float red[8];
    bf16* row = ratt + (size_t)b*2048;
    float v[8];
    float mx = -1e30f;
    #pragma unroll
    for (int j = 0; j < 8; j++) {
        v[j] = __bfloat162float(row[t + j*256]);
        mx = fmaxf(mx, v[j]);
    }
    #pragma unroll
    for (int off = 32; off; off >>= 1) mx = fmaxf(mx, __shfl_xor(mx, off));
    if (lane == 0) red[w] = mx;
    __syncthreads();
    mx = fmaxf(fmaxf(red[0], red[1]), fmaxf(red[2], red[3]));
    float s = 0.f;
    #pragma unroll
    for (int j = 0; j < 8; j++) { v[j] = __expf(v[j] - mx); s += v[j]; }
    #pragma unroll
    for (int off = 32; off; off >>= 1) s += __shfl_xor(s, off);
    if (lane == 0) red[4 + w] = s;
    __syncthreads();
    float inv = 1.f / (red[4] + red[5] + red[6] + red[7]);
    #pragma unroll
    for (int j = 0; j < 8; j++)
        row[t + j*256] = __float2bfloat16(v[j] * inv);
}

// ---------------- column-mean partials: coalesced row-wise reads ----------------
// grid (12, 8): block (ct, rc). ct<8 -> ratt cols; ct>=8 -> cand cols. 128 rows per rc.
__global__ __launch_bounds__(256) void k_colpart(const bf16* __restrict__ ratt,
                                                 const bf16* __restrict__ cand,
                                                 float* __restrict__ part) {
    int ct = blockIdx.x, rc = blockIdx.y, t = threadIdx.x;
    int col = ct*256 + t;                 // global 0..3071
    const bf16* src; int stride, c;
    if (ct < 8) { src = ratt; stride = 2048; c = col; }
    else        { src = cand; stride = 1024; c = col - 2048; }
    float s = 0.f;
    int r0 = rc*128;
    for (int r = 0; r < 128; r++)
        s += __bfloat162float(src[(size_t)(r0 + r)*stride + c]);
    part[rc*3072 + col] = s;
}

__global__ __launch_bounds__(256) void k_colfin(const float* __restrict__ part,
                                                const float* __restrict__ update_gate,
                                                float* __restrict__ u,
                                                float* __restrict__ cmean) {
    int col = blockIdx.x*256 + threadIdx.x;   // 0..3071
    float s = 0.f;
    #pragma unroll
    for (int rc = 0; rc < 8; rc++) s += part[rc*3072 + col];
    s *= (1.f/1024.f);
    if (col < 2048) u[col] = s * update_gate[col];
    else            cmean[col - 2048] = s;
}

// ---------------- new_mem blend (f32 out) ----------------
__global__ __launch_bounds__(256) void k_newmem(const float* __restrict__ mem,
                                                const float* __restrict__ u,
                                                const float* __restrict__ cmean,
                                                float* __restrict__ out1) {
    int idx = blockIdx.x*256 + threadIdx.x;       // 2M
    int m = idx >> 10, d = idx & 1023;
    float um = u[m];
    out1[idx] = mem[idx] * (1.f - um) + um * cmean[d];
}

// ---------------- critic + final gating: 4 batch rows per block ----------------
// feature j computed by lane-group: j = t&31 (coalesced weight reads), k-group g = t>>5.
__global__ __launch_bounds__(256) void k_critic(
        const float* __restrict__ readv, const float* __restrict__ preds,
        const bf16* __restrict__ hidden,
        const float* cw1, const float* cb1, const float* cw2, const float* cb2,
        const float* cw3, const float* cb3, const float* cw4, const float* cb4,
        const float* cw5, const float* cb5, const float* thr,
        float* __restrict__ out0) {
    __shared__ float part4[4][8][32];
    __shared__ float feat4[4][96];
    __shared__ float fused4[4][64];
    __shared__ float gsh4[4];
    int b0 = blockIdx.x * 4, t = threadIdx.x;
    int j = t & 31, g = t >> 5;

    // f1: readv (K=1024) @ cw1 (1024x32)
    {
        float acc[4] = {0.f, 0.f, 0.f, 0.f};
        for (int k = g; k < 1024; k += 8) {
            float wv = cw1[k*32 + j];
            #pragma unroll
            for (int r = 0; r < 4; r++) acc[r] += readv[(size_t)(b0 + r)*1024 + k] * wv;
        }
        #pragma unroll
        for (int r = 0; r < 4; r++) part4[r][g][j] = acc[r];
    }
    __syncthreads();
    if (t < 128) {
        int r = t >> 5, jj = t & 31;
        float tot = 0.f;
        #pragma unroll
        for (int i = 0; i < 8; i++) tot += part4[r][i][jj];
        feat4[r][jj] = fmaxf(tot + cb1[jj], 0.f);
    }
    __syncthreads();
    // f2: preds (K=512) @ cw2 (512x32)
    {
        float acc[4] = {0.f, 0.f, 0.f, 0.f};
        for (int k = g; k < 512; k += 8) {
            float wv = cw2[k*32 + j];
            #pragma unroll
            for (int r = 0; r < 4; r++) acc[r] += preds[(size_t)(b0 + r)*512 + k] * wv;
        }
        #pragma unroll
        for (int r = 0; r < 4; r++) part4[r][g][j] = acc[r];
    }
    __syncthreads();
    if (t < 128) {
        int r = t >> 5, jj = t & 31;
        float tot = 0.f;
        #pragma unroll
        for (int i = 0; i < 8; i++) tot += part4[r][i][jj];
        feat4[r][32 + jj] = fmaxf(tot + cb2[jj], 0.f);
    }
    __syncthreads();
    // f3: hidden bf16 (K=2048) @ cw3 (2048x32)
    {
        float acc[4] = {0.f, 0.f, 0.f, 0.f};
        for (int k = g; k < 2048; k += 8) {
            float wv = cw3[k*32 + j];
            #pragma unroll
            for (int r = 0; r < 4; r++)
                acc[r] += __bfloat162float(hidden[(size_t)(b0 + r)*2048 + k]) * wv;
        }
        #pragma unroll
        for (int r = 0; r < 4; r++) part4[r][g][j] = acc[r];
    }
    __syncthreads();
    if (t < 128) {
        int r = t >> 5, jj = t & 31;
        float tot = 0.f;
        #pragma unroll
        for (int i = 0; i < 8; i++) tot += part4[r][i][jj];
        feat4[r][64 + jj] = fmaxf(tot + cb3[jj], 0.f);
    }
    __syncthreads();
    // fused = relu(feat @ cw4 + cb4): thread t -> row r=t>>6, unit u=t&63
    {
        int r = t >> 6, uu = t & 63;
        float s = 0.f;
        #pragma unroll 8
        for (int k = 0; k < 96; k++) s += feat4[r][k] * cw4[k*64 + uu];
        fused4[r][uu] = fmaxf(s + cb4[uu], 0.f);
    }
    __syncthreads();
    // gating scalar per row: wave w handles row w
    {
        int w = t >> 6, lane = t & 63;
        float v = fused4[w][lane] * cw5[lane*2];
        #pragma unroll
        for (int off = 32; off; off >>= 1) v += __shfl_xor(v, off);
        if (lane == 0)
            gsh4[w] = 1.f / (1.f + __expf(-(v + cb5[0] - thr[0])));
    }
    __syncthreads();
    for (int idx = t; idx < 4*512; idx += 256) {
        int r = idx >> 9, o = idx & 511;
        out0[(size_t)(b0 + r)*512 + o] = preds[(size_t)(b0 + r)*512 + o] * gsh4[r];
    }
}

extern "C" void kernel_launch(void* const* d_in, const int* in_sizes, int n_in,
                              void* d_out, int out_size, void* d_ws, size_t ws_size,
                              hipStream_t stream) {
    const float* x        = (const float*)d_in[0];
    const float* w_       = (const float*)d_in[1];   // (1024, 2048*4) row-major
    const float* b_bias   = (const float*)d_in[2];   // (2048*4)
    const float* gate_w   = (const float*)d_in[3];
    const float* gate_b   = (const float*)d_in[4];
    const float* act_w    = (const float*)d_in[5];
    const float* mask     = (const float*)d_in[6];
    const float* mem      = (const float*)d_in[7];   // (2048, 1024)
    const float* att_w    = (const float*)d_in[8];   // (2048, 2048)
    const float* att_b    = (const float*)d_in[9];
    const float* write_w  = (const float*)d_in[10];  // (2048, 1024)
    const float* write_b  = (const float*)d_in[11];
    const float* upd_gate = (const float*)d_in[12];
    const float* out_w    = (const float*)d_in[13];  // (2048, 512)
    const float* out_b    = (const float*)d_in[14];
    const float* cw1 = (const float*)d_in[15]; const float* cb1 = (const float*)d_in[16];
    const float* cw2 = (const float*)d_in[17]; const float* cb2 = (const float*)d_in[18];
    const float* cw3 = (const float*)d_in[19]; const float* cb3 = (const float*)d_in[20];
    const float* cw4 = (const float*)d_in[21]; const float* cb4 = (const float*)d_in[22];
    const float* cw5 = (const float*)d_in[23]; const float* cb5 = (const float*)d_in[24];
    const float* thr = (const float*)d_in[25];

    char* ws = (char*)d_ws;
    float* gate   = (float*)(ws + GATE_OFF);
    float* actw   = (float*)(ws + ACTW_OFF);
    float* uvec   = (float*)(ws + U_OFF);
    float* cmean  = (float*)(ws + CMEAN_OFF);
    float* part   = (float*)(ws + PART_OFF);
    bf16*  hidden = (bf16*)(ws + HIDDEN_OFF);
    bf16*  ratt   = (bf16*)(ws + RATT_OFF);
    bf16*  cand   = (bf16*)(ws + CAND_OFF);
    float* preds  = (float*)(ws + PREDS_OFF);
    float* readv  = (float*)(ws + READ_OFF);

    float* out0 = (float*)d_out;            // (1024, 512)
    float* out1 = out0 + 1024*512;          // (2048, 1024)

    k_gate<<<1024, 256, 0, stream>>>(x, gate_w, gate_b, act_w, gate, actw);

    // hidden = qact((x@w + b)·gate) * mask        [M=1024, N=8192, K=1024]
    gemm_nn<4, 1><<<dim3(64, 8), 256, 0, stream>>>(x, w_, 1024, 8192,
        b_bias, nullptr, hidden, gate, actw, mask, 2048);
    // att logits = hidden @ att_w + att_b         [M=1024, N=2048, K=2048]
    gemm_nn<0, 0><<<dim3(16, 8), 256, 0, stream>>>(hidden, att_w, 2048, 2048,
        att_b, nullptr, ratt, nullptr, nullptr, nullptr, 2048);
    k_softmax<<<1024, 256, 0, stream>>>(ratt);
    // cand = tanh(hidden @ write_w + write_b)     [M=1024, N=1024, K=2048]
    gemm_nn<1, 0><<<dim3(8, 8), 256, 0, stream>>>(hidden, write_w, 2048, 1024,
        write_b, nullptr, cand, nullptr, nullptr, nullptr, 1024);
    // preds = hidden @ out_w + out_b (f32)        [M=1024, N=512, K=2048]
    gemm_nn<2, 0><<<dim3(4, 8), 256, 0, stream>>>(hidden, out_w, 2048, 512,
        out_b, preds, nullptr, nullptr, nullptr, nullptr, 512);
    // read = ratt @ mem (f32)                     [M=1024, N=1024, K=2048]
    gemm_nn<3, 0><<<dim3(8, 8), 256, 0, stream>>>(ratt, mem, 2048, 1024,
        nullptr, readv, nullptr, nullptr, nullptr, nullptr, 1024);

    k_colpart<<<dim3(12, 8), 256, 0, stream>>>(ratt, cand, part);
    k_colfin<<<12, 256, 0, stream>>>(part, upd_gate, uvec, cmean);
    k_newmem<<<8192, 256, 0, stream>>>(mem, uvec, cmean, out1);
    k_critic<<<256, 256, 0, stream>>>(readv, preds, hidden,
        cw1, cb1, cw2, cb2, cw3, cb3, cw4, cb4, cw5, cb5, thr, out0);
}

// Round 6
// 582.505 us; speedup vs baseline: 1.1202x; 1.1202x over previous
//
#include <hip/hip_runtime.h>
#include <hip/hip_bf16.h>
#include <math.h>

typedef __attribute__((ext_vector_type(4))) float f32x4;
typedef __attribute__((ext_vector_type(8))) short s16x8;
typedef __hip_bfloat16 bf16;

#define MB (1024ull*1024ull)
// workspace layout (bytes) — total 17 MB
#define GATE_OFF    (0ull)          // 1024*4 f32 = 16KB
#define ACTW_OFF    (16ull*1024)    // 9 f32
#define U_OFF       (20ull*1024)    // 2048 f32
#define CMEAN_OFF   (28ull*1024)    // 1024 f32
#define PART_OFF    (64ull*1024)    // 8*3072 f32 = 96KB (col-mean partials)
#define HIDDEN_OFF  (1ull*MB)       // bf16 1024x2048 (4MB)
#define RATT_OFF    (5ull*MB)       // bf16 1024x2048 (4MB) logits -> softmax in-place
#define CAND_OFF    (9ull*MB)       // bf16 1024x1024 (2MB)
#define PREDS_OFF   (11ull*MB)      // f32 1024x512  (2MB)
#define READ_OFF    (13ull*MB)      // f32 1024x1024 (4MB) -> ends 17MB

__device__ __forceinline__ short f2bf_s(float f) {
    bf16 h = __float2bfloat16(f);
    return *reinterpret_cast<short*>(&h);
}

__device__ __forceinline__ float qact(float x, const float* w) {
    float ex  = __expf(x);
    float sig = 1.f / (1.f + __expf(-x));
    float elu = x > 0.f ? x : ex - 1.f;
    float th  = tanhf(x);
    float rel = fmaxf(x, 0.f);
    float silu = x * sig;
    float gel = 0.5f * x * (1.f + erff(x * 0.70710678118654752f));
    float sel = 1.0507009873554805f * (x > 0.f ? x : 1.6732632423543772f * (ex - 1.f));
    float sp  = (x > 15.f) ? x : log1pf(ex);
    float mish = x * tanhf(sp);
    return w[0]*sig + w[1]*elu + w[2]*th + w[3]*rel + w[4]*silu
         + w[5]*gel + w[6]*sel + w[7]*mish + w[8]*x;
}

// ---------------- gate softmax + act-weight softmax (all f32) ----------------
__global__ __launch_bounds__(256) void k_gate(const float* __restrict__ x,
                                              const float* __restrict__ gw,
                                              const float* __restrict__ gb,
                                              const float* __restrict__ aw_in,
                                              float* __restrict__ gate,
                                              float* __restrict__ actw) {
    int b = blockIdx.x, t = threadIdx.x, w = t >> 6, lane = t & 63;
    __shared__ float l[4];
    float s = 0.f;
    for (int k = lane; k < 1024; k += 64)
        s += x[(size_t)b*1024 + k] * gw[k*4 + w];
    #pragma unroll
    for (int off = 32; off; off >>= 1) s += __shfl_xor(s, off);
    if (lane == 0) l[w] = s + gb[w];
    __syncthreads();
    if (t == 0) {
        float m = fmaxf(fmaxf(l[0], l[1]), fmaxf(l[2], l[3]));
        float e0 = __expf(l[0]-m), e1 = __expf(l[1]-m), e2 = __expf(l[2]-m), e3 = __expf(l[3]-m);
        float inv = 1.f / (e0+e1+e2+e3);
        gate[b*4+0] = e0*inv; gate[b*4+1] = e1*inv;
        gate[b*4+2] = e2*inv; gate[b*4+3] = e3*inv;
    }
    if (b == 0 && t == 64) {
        float a[9]; float m = -1e30f;
        for (int i = 0; i < 9; i++) { a[i] = aw_in[i]; m = fmaxf(m, a[i]); }
        float ss = 0.f;
        for (int i = 0; i < 9; i++) { a[i] = __expf(a[i]-m); ss += a[i]; }
        float inv = 1.f / ss;
        for (int i = 0; i < 9; i++) actw[i] = a[i]*inv;
    }
}

// ---------------- GEMM (NN): C(MxN) = A(MxK) @ B(KxN), 128x128 tile, BK=32 ----------------
// (HW-validated round 4 — unchanged)
template <int MODE, int AF32>
__global__ __launch_bounds__(256, 2) void gemm_nn(
        const void* __restrict__ Av, const float* __restrict__ B,
        int K, int ldb,
        const float* __restrict__ bias,
        float* __restrict__ outF, bf16* __restrict__ outH,
        const float* __restrict__ gate, const float* __restrict__ actw,
        const float* __restrict__ mask, int outStride) {
    __shared__ __align__(16) short sA[128*32];
    __shared__ __align__(16) short sB[128*32];
    int t = threadIdx.x, lane = t & 63;
    int rowBase = blockIdx.y * 128, colBase = blockIdx.x * 128;
    int lm = lane & 15, lq = lane >> 4;
    int w = t >> 6;
    int qm = (w >> 1) * 64, qn = (w & 1) * 64;

    f32x4 acc[4][4];
    #pragma unroll
    for (int i = 0; i < 4; i++)
        #pragma unroll
        for (int j = 0; j < 4; j++) acc[i][j] = (f32x4){0.f, 0.f, 0.f, 0.f};

    int ar = t >> 2, ak = (t & 3) * 8;
    int bk = t >> 3, bn0 = (t & 7) * 16;
    int swz = (((t >> 6) ^ (t & 3)) << 3) | (bk & 7);

    for (int k0 = 0; k0 < K; k0 += 32) {
        __syncthreads();
        if (AF32) {
            const float* Af = (const float*)Av;
            #pragma unroll
            for (int h = 0; h < 2; h++) {
                int r = ar + h*64;
                const float* src = Af + (size_t)(rowBase + r)*K + k0 + ak;
                s16x8 av;
                #pragma unroll
                for (int j = 0; j < 8; j++) av[j] = f2bf_s(src[j]);
                *reinterpret_cast<s16x8*>(sA + r*32 + ak) = av;
            }
        } else {
            const bf16* Ab = (const bf16*)Av;
            *reinterpret_cast<s16x8*>(sA + ar*32 + ak) =
                *reinterpret_cast<const s16x8*>(Ab + (size_t)(rowBase + ar)*K + k0 + ak);
            *reinterpret_cast<s16x8*>(sA + (ar + 64)*32 + ak) =
                *reinterpret_cast<const s16x8*>(Ab + (size_t)(rowBase + ar + 64)*K + k0 + ak);
        }
        const float* bsrc = B + (size_t)(k0 + bk)*ldb + colBase + bn0;
        #pragma unroll
        for (int j = 0; j < 16; j++)
            sB[(bn0 + j)*32 + swz] = f2bf_s(bsrc[j]);
        __syncthreads();
        s16x8 af[4], bfr[4];
        #pragma unroll
        for (int mi = 0; mi < 4; mi++)
            af[mi] = *reinterpret_cast<const s16x8*>(sA + (qm + mi*16 + lm)*32 + lq*8);
        #pragma unroll
        for (int ni = 0; ni < 4; ni++) {
            int n = qn + ni*16 + lm;
            bfr[ni] = *reinterpret_cast<const s16x8*>(sB + n*32 + ((lq ^ ni) << 3));
        }
        #pragma unroll
        for (int mi = 0; mi < 4; mi++)
            #pragma unroll
            for (int ni = 0; ni < 4; ni++)
                acc[mi][ni] = __builtin_amdgcn_mfma_f32_16x16x32_bf16(af[mi], bfr[ni], acc[mi][ni], 0, 0, 0);
    }

    if (MODE == 4) {
        float aw[9];
        #pragma unroll
        for (int i = 0; i < 9; i++) aw[i] = actw[i];
        #pragma unroll
        for (int mi = 0; mi < 4; mi++) {
            int row0 = rowBase + qm + mi*16 + lq*4;
            #pragma unroll
            for (int ni = 0; ni < 4; ni++) {
                int col = colBase + qn + ni*16 + lm;
                int n = col & 3;
                float bb = bias[col];
                f32x4 v = acc[mi][ni];
                #pragma unroll
                for (int r = 0; r < 4; r++) v[r] = (v[r] + bb) * gate[(row0 + r)*4 + n];
                #pragma unroll
                for (int r = 0; r < 4; r++) v[r] += __shfl_xor(v[r], 1);
                #pragma unroll
                for (int r = 0; r < 4; r++) v[r] += __shfl_xor(v[r], 2);
                if ((lane & 3) == 0) {
                    int uu = col >> 2;
                    float mk = mask[uu];
                    #pragma unroll
                    for (int r = 0; r < 4; r++)
                        outH[(size_t)(row0 + r)*outStride + uu] = __float2bfloat16(qact(v[r], aw) * mk);
                }
            }
        }
    } else {
        #pragma unroll
        for (int mi = 0; mi < 4; mi++) {
            int row0 = rowBase + qm + mi*16 + lq*4;
            #pragma unroll
            for (int ni = 0; ni < 4; ni++) {
                int col = colBase + qn + ni*16 + lm;
                float bb = (MODE == 3) ? 0.f : bias[col];
                #pragma unroll
                for (int r = 0; r < 4; r++) {
                    float vv = acc[mi][ni][r] + bb;
                    size_t oi = (size_t)(row0 + r)*outStride + col;
                    if (MODE == 0) outH[oi] = __float2bfloat16(vv);
                    if (MODE == 1) outH[oi] = __float2bfloat16(tanhf(vv));
                    if (MODE == 2 || MODE == 3) outF[oi] = vv;
                }
            }
        }
    }
}

// ---------------- in-place row softmax over 2048 cols (bf16 buffer) ----------------
__global__ __launch_bounds__(256) void k_softmax(bf16* __restrict__ ratt) {
    int b = blockIdx.x, t = threadIdx.x, w = t >> 6, lane = t & 63;
    __shared__ float red[8];
    bf16* row = ratt + (size_t)b*2048;
    float v[8];
    float mx = -1e30f;
    #pragma unroll
    for (int j = 0; j < 8; j++) {
        v[j] = __bfloat162float(row[t + j*256]);
        mx = fmaxf(mx, v[j]);
    }
    #pragma unroll
    for (int off = 32; off; off >>= 1) mx = fmaxf(mx, __shfl_xor(mx, off));
    if (lane == 0) red[w] = mx;
    __syncthreads();
    mx = fmaxf(fmaxf(red[0], red[1]), fmaxf(red[2], red[3]));
    float s = 0.f;
    #pragma unroll
    for (int j = 0; j < 8; j++) { v[j] = __expf(v[j] - mx); s += v[j]; }
    #pragma unroll
    for (int off = 32; off; off >>= 1) s += __shfl_xor(s, off);
    if (lane == 0) red[4 + w] = s;
    __syncthreads();
    float inv = 1.f / (red[4] + red[5] + red[6] + red[7]);
    #pragma unroll
    for (int j = 0; j < 8; j++)
        row[t + j*256] = __float2bfloat16(v[j] * inv);
}

// ---------------- column-mean partials: coalesced row-wise reads ----------------
__global__ __launch_bounds__(256) void k_colpart(const bf16* __restrict__ ratt,
                                                 const bf16* __restrict__ cand,
                                                 float* __restrict__ part) {
    int ct = blockIdx.x, rc = blockIdx.y, t = threadIdx.x;
    int col = ct*256 + t;                 // global 0..3071
    const bf16* src; int stride, c;
    if (ct < 8) { src = ratt; stride = 2048; c = col; }
    else        { src = cand; stride = 1024; c = col - 2048; }
    float s = 0.f;
    int r0 = rc*128;
    for (int r = 0; r < 128; r++)
        s += __bfloat162float(src[(size_t)(r0 + r)*stride + c]);
    part[rc*3072 + col] = s;
}

__global__ __launch_bounds__(256) void k_colfin(const float* __restrict__ part,
                                                const float* __restrict__ update_gate,
                                                float* __restrict__ u,
                                                float* __restrict__ cmean) {
    int col = blockIdx.x*256 + threadIdx.x;   // 0..3071
    float s = 0.f;
    #pragma unroll
    for (int rc = 0; rc < 8; rc++) s += part[rc*3072 + col];
    s *= (1.f/1024.f);
    if (col < 2048) u[col] = s * update_gate[col];
    else            cmean[col - 2048] = s;
}

// ---------------- new_mem blend (f32 out) ----------------
__global__ __launch_bounds__(256) void k_newmem(const float* __restrict__ mem,
                                                const float* __restrict__ u,
                                                const float* __restrict__ cmean,
                                                float* __restrict__ out1) {
    int idx = blockIdx.x*256 + threadIdx.x;       // 2M
    int m = idx >> 10, d = idx & 1023;
    float um = u[m];
    out1[idx] = mem[idx] * (1.f - um) + um * cmean[d];
}

// ---------------- critic + final gating: 1 batch row per block, LDS-staged ----------------
// Occupancy-first design (round-5 lesson: latency-bound => need waves).
// 1024 blocks x 4 waves = 16 waves/CU. Weight reads coalesced (lane group j = t&31),
// activations broadcast from LDS, serial depth only K/8 per feature chunk.
__global__ __launch_bounds__(256) void k_critic(
        const float* __restrict__ readv, const float* __restrict__ preds,
        const bf16* __restrict__ hidden,
        const float* cw1, const float* cb1, const float* cw2, const float* cb2,
        const float* cw3, const float* cb3, const float* cw4, const float* cb4,
        const float* cw5, const float* cb5, const float* thr,
        float* __restrict__ out0) {
    __shared__ __align__(16) float sx[1024];   // readv row
    __shared__ __align__(16) float sp[512];    // preds row
    __shared__ __align__(16) short sh[2048];   // hidden row (bf16 bits)
    __shared__ float part[8][32];
    __shared__ float feat[96];
    __shared__ float fused[64];
    __shared__ float gsh;
    int b = blockIdx.x, t = threadIdx.x;
    int j = t & 31, g = t >> 5;

    // ---- stage activations (16B vector loads) ----
    ((f32x4*)sx)[t] = ((const f32x4*)(readv + (size_t)b*1024))[t];          // 256*16B = 4KB
    if (t < 128) ((f32x4*)sp)[t] = ((const f32x4*)(preds + (size_t)b*512))[t];
    ((s16x8*)sh)[t] = ((const s16x8*)(hidden + (size_t)b*2048))[t];         // 256*16B = 4KB
    __syncthreads();

    // ---- f1: readv(1024) @ cw1(1024x32) ----
    {
        float a = 0.f;
        int k0 = g*128;
        #pragma unroll 4
        for (int k = k0; k < k0 + 128; k++) a += sx[k] * cw1[k*32 + j];
        part[g][j] = a;
    }
    __syncthreads();
    if (t < 32) {
        float s = 0.f;
        #pragma unroll
        for (int i = 0; i < 8; i++) s += part[i][t];
        feat[t] = fmaxf(s + cb1[t], 0.f);
    }
    __syncthreads();
    // ---- f2: preds(512) @ cw2(512x32) ----
    {
        float a = 0.f;
        int k0 = g*64;
        #pragma unroll 4
        for (int k = k0; k < k0 + 64; k++) a += sp[k] * cw2[k*32 + j];
        part[g][j] = a;
    }
    __syncthreads();
    if (t < 32) {
        float s = 0.f;
        #pragma unroll
        for (int i = 0; i < 8; i++) s += part[i][t];
        feat[32 + t] = fmaxf(s + cb2[t], 0.f);
    }
    __syncthreads();
    // ---- f3: hidden(2048,bf16) @ cw3(2048x32) ----
    {
        float a = 0.f;
        int k0 = g*256;
        #pragma unroll 4
        for (int k = k0; k < k0 + 256; k++) {
            bf16 hv = *reinterpret_cast<const bf16*>(&sh[k]);
            a += __bfloat162float(hv) * cw3[k*32 + j];
        }
        part[g][j] = a;
    }
    __syncthreads();
    if (t < 32) {
        float s = 0.f;
        #pragma unroll
        for (int i = 0; i < 8; i++) s += part[i][t];
        feat[64 + t] = fmaxf(s + cb3[t], 0.f);
    }
    __syncthreads();
    // ---- fused = relu(feat @ cw4 + cb4) ----
    if (t < 64) {
        float s = 0.f;
        #pragma unroll 8
        for (int k = 0; k < 96; k++) s += feat[k] * cw4[k*64 + t];
        fused[t] = fmaxf(s + cb4[t], 0.f);
    }
    __syncthreads();
    // ---- gating scalar (wave 0) ----
    if (t < 64) {
        float v = fused[t] * cw5[t*2];
        #pragma unroll
        for (int off = 32; off; off >>= 1) v += __shfl_xor(v, off);
        if (t == 0)
            gsh = 1.f / (1.f + __expf(-(v + cb5[0] - thr[0])));
    }
    __syncthreads();
    float gg = gsh;
    #pragma unroll
    for (int o = t; o < 512; o += 256)
        out0[(size_t)b*512 + o] = sp[o] * gg;
}

extern "C" void kernel_launch(void* const* d_in, const int* in_sizes, int n_in,
                              void* d_out, int out_size, void* d_ws, size_t ws_size,
                              hipStream_t stream) {
    const float* x        = (const float*)d_in[0];
    const float* w_       = (const float*)d_in[1];   // (1024, 2048*4) row-major
    const float* b_bias   = (const float*)d_in[2];   // (2048*4)
    const float* gate_w   = (const float*)d_in[3];
    const float* gate_b   = (const float*)d_in[4];
    const float* act_w    = (const float*)d_in[5];
    const float* mask     = (const float*)d_in[6];
    const float* mem      = (const float*)d_in[7];   // (2048, 1024)
    const float* att_w    = (const float*)d_in[8];   // (2048, 2048)
    const float* att_b    = (const float*)d_in[9];
    const float* write_w  = (const float*)d_in[10];  // (2048, 1024)
    const float* write_b  = (const float*)d_in[11];
    const float* upd_gate = (const float*)d_in[12];
    const float* out_w    = (const float*)d_in[13];  // (2048, 512)
    const float* out_b    = (const float*)d_in[14];
    const float* cw1 = (const float*)d_in[15]; const float* cb1 = (const float*)d_in[16];
    const float* cw2 = (const float*)d_in[17]; const float* cb2 = (const float*)d_in[18];
    const float* cw3 = (const float*)d_in[19]; const float* cb3 = (const float*)d_in[20];
    const float* cw4 = (const float*)d_in[21]; const float* cb4 = (const float*)d_in[22];
    const float* cw5 = (const float*)d_in[23]; const float* cb5 = (const float*)d_in[24];
    const float* thr = (const float*)d_in[25];

    char* ws = (char*)d_ws;
    float* gate   = (float*)(ws + GATE_OFF);
    float* actw   = (float*)(ws + ACTW_OFF);
    float* uvec   = (float*)(ws + U_OFF);
    float* cmean  = (float*)(ws + CMEAN_OFF);
    float* part   = (float*)(ws + PART_OFF);
    bf16*  hidden = (bf16*)(ws + HIDDEN_OFF);
    bf16*  ratt   = (bf16*)(ws + RATT_OFF);
    bf16*  cand   = (bf16*)(ws + CAND_OFF);
    float* preds  = (float*)(ws + PREDS_OFF);
    float* readv  = (float*)(ws + READ_OFF);

    float* out0 = (float*)d_out;            // (1024, 512)
    float* out1 = out0 + 1024*512;          // (2048, 1024)

    k_gate<<<1024, 256, 0, stream>>>(x, gate_w, gate_b, act_w, gate, actw);

    // hidden = qact((x@w + b)·gate) * mask        [M=1024, N=8192, K=1024]
    gemm_nn<4, 1><<<dim3(64, 8), 256, 0, stream>>>(x, w_, 1024, 8192,
        b_bias, nullptr, hidden, gate, actw, mask, 2048);
    // att logits = hidden @ att_w + att_b         [M=1024, N=2048, K=2048]
    gemm_nn<0, 0><<<dim3(16, 8), 256, 0, stream>>>(hidden, att_w, 2048, 2048,
        att_b, nullptr, ratt, nullptr, nullptr, nullptr, 2048);
    k_softmax<<<1024, 256, 0, stream>>>(ratt);
    // cand = tanh(hidden @ write_w + write_b)     [M=1024, N=1024, K=2048]
    gemm_nn<1, 0><<<dim3(8, 8), 256, 0, stream>>>(hidden, write_w, 2048, 1024,
        write_b, nullptr, cand, nullptr, nullptr, nullptr, 1024);
    // preds = hidden @ out_w + out_b (f32)        [M=1024, N=512, K=2048]
    gemm_nn<2, 0><<<dim3(4, 8), 256, 0, stream>>>(hidden, out_w, 2048, 512,
        out_b, preds, nullptr, nullptr, nullptr, nullptr, 512);
    // read = ratt @ mem (f32)                     [M=1024, N=1024, K=2048]
    gemm_nn<3, 0><<<dim3(8, 8), 256, 0, stream>>>(ratt, mem, 2048, 1024,
        nullptr, readv, nullptr, nullptr, nullptr, nullptr, 1024);

    k_colpart<<<dim3(12, 8), 256, 0, stream>>>(ratt, cand, part);
    k_colfin<<<12, 256, 0, stream>>>(part, upd_gate, uvec, cmean);
    k_newmem<<<8192, 256, 0, stream>>>(mem, uvec, cmean, out1);
    k_critic<<<1024, 256, 0, stream>>>(readv, preds, hidden,
        cw1, cb1, cw2, cb2, cw3, cb3, cw4, cb4, cw5, cb5, thr, out0);
}

// Round 7
// 493.253 us; speedup vs baseline: 1.3229x; 1.1809x over previous
//
#include <hip/hip_runtime.h>
#include <hip/hip_bf16.h>
#include <math.h>

typedef __attribute__((ext_vector_type(4))) float f32x4;
typedef __attribute__((ext_vector_type(8))) short s16x8;
typedef __attribute__((ext_vector_type(4))) short s16x4;
typedef __hip_bfloat16 bf16;

#define MB (1024ull*1024ull)
// workspace layout (bytes) — total 53 MB
#define GATE_OFF    (0ull)          // 1024*4 f32
#define ACTW_OFF    (16ull*1024)    // 9 f32
#define U_OFF       (20ull*1024)    // 2048 f32
#define CMEAN_OFF   (28ull*1024)    // 1024 f32
#define PART_OFF    (64ull*1024)    // 8*3072 f32
#define HIDDEN_OFF  (1ull*MB)       // bf16 1024x2048 (4MB)
#define RATT_OFF    (5ull*MB)       // bf16 1024x2048 (4MB)
#define CAND_OFF    (9ull*MB)       // bf16 1024x1024 (2MB)
#define PREDS_OFF   (11ull*MB)      // f32 1024x512  (2MB)
#define READ_OFF    (13ull*MB)      // f32 1024x1024 (4MB)
#define XBF_OFF     (17ull*MB)      // bf16 1024x1024 (2MB)
#define WT_OFF      (19ull*MB)      // bf16 8192x1024 (16MB)
#define ATTWT_OFF   (35ull*MB)      // bf16 2048x2048 (8MB)
#define WRITEWT_OFF (43ull*MB)      // bf16 1024x2048 (4MB)
#define OUTWT_OFF   (47ull*MB)      // bf16 512x2048 (2MB)
#define MEMT_OFF    (49ull*MB)      // bf16 1024x2048 (4MB) -> ends 53MB

__device__ __forceinline__ short f2bf_s(float f) {
    bf16 h = __float2bfloat16(f);
    return *reinterpret_cast<short*>(&h);
}

__device__ __forceinline__ float qact(float x, const float* w) {
    float ex  = __expf(x);
    float sig = 1.f / (1.f + __expf(-x));
    float elu = x > 0.f ? x : ex - 1.f;
    float th  = tanhf(x);
    float rel = fmaxf(x, 0.f);
    float silu = x * sig;
    float gel = 0.5f * x * (1.f + erff(x * 0.70710678118654752f));
    float sel = 1.0507009873554805f * (x > 0.f ? x : 1.6732632423543772f * (ex - 1.f));
    float sp  = (x > 15.f) ? x : log1pf(ex);
    float mish = x * tanhf(sp);
    return w[0]*sig + w[1]*elu + w[2]*th + w[3]*rel + w[4]*silu
         + w[5]*gel + w[6]*sel + w[7]*mish + w[8]*x;
}

// ---------------- fp32 (R x C) -> bf16 (C x R) transpose, 64x64 tiles ----------------
__global__ __launch_bounds__(256) void k_transpose(const float* __restrict__ in,
                                                   bf16* __restrict__ out, int R, int C) {
    __shared__ short tile[64][66];
    int k0 = blockIdx.y*64, n0 = blockIdx.x*64;
    int tx = threadIdx.x, ty = threadIdx.y;     // (64,4)
    #pragma unroll
    for (int j = 0; j < 16; j++) {
        int k = ty + j*4;
        tile[tx][k] = f2bf_s(in[(size_t)(k0 + k)*C + n0 + tx]);
    }
    __syncthreads();
    int t = ty*64 + tx;
    int kp = t & 31, nrow = t >> 5;             // kp: packed-pair idx, nrow 0..7
    #pragma unroll
    for (int jj = 0; jj < 8; jj++) {
        int n = nrow + jj*8;
        unsigned lo = (unsigned short)tile[n][kp*2];
        unsigned hi = (unsigned short)tile[n][kp*2 + 1];
        *reinterpret_cast<unsigned*>(&out[(size_t)(n0 + n)*R + k0 + kp*2]) = lo | (hi << 16);
    }
}

// ---------------- fp32 -> bf16 flat convert (n = multiple of 1024) ----------------
__global__ __launch_bounds__(256) void k_cvt(const float* __restrict__ in,
                                             bf16* __restrict__ out) {
    int i = blockIdx.x*256 + threadIdx.x;
    f32x4 v = ((const f32x4*)in)[i];
    s16x4 o;
    #pragma unroll
    for (int j = 0; j < 4; j++) o[j] = f2bf_s(v[j]);
    ((s16x4*)out)[i] = o;
}

// ---------------- gate softmax + act-weight softmax (all f32) ----------------
__global__ __launch_bounds__(256) void k_gate(const float* __restrict__ x,
                                              const float* __restrict__ gw,
                                              const float* __restrict__ gb,
                                              const float* __restrict__ aw_in,
                                              float* __restrict__ gate,
                                              float* __restrict__ actw) {
    int b = blockIdx.x, t = threadIdx.x, w = t >> 6, lane = t & 63;
    __shared__ float l[4];
    float s = 0.f;
    for (int k = lane; k < 1024; k += 64)
        s += x[(size_t)b*1024 + k] * gw[k*4 + w];
    #pragma unroll
    for (int off = 32; off; off >>= 1) s += __shfl_xor(s, off);
    if (lane == 0) l[w] = s + gb[w];
    __syncthreads();
    if (t == 0) {
        float m = fmaxf(fmaxf(l[0], l[1]), fmaxf(l[2], l[3]));
        float e0 = __expf(l[0]-m), e1 = __expf(l[1]-m), e2 = __expf(l[2]-m), e3 = __expf(l[3]-m);
        float inv = 1.f / (e0+e1+e2+e3);
        gate[b*4+0] = e0*inv; gate[b*4+1] = e1*inv;
        gate[b*4+2] = e2*inv; gate[b*4+3] = e3*inv;
    }
    if (b == 0 && t == 64) {
        float a[9]; float m = -1e30f;
        for (int i = 0; i < 9; i++) { a[i] = aw_in[i]; m = fmaxf(m, a[i]); }
        float ss = 0.f;
        for (int i = 0; i < 9; i++) { a[i] = __expf(a[i]-m); ss += a[i]; }
        float inv = 1.f / ss;
        for (int i = 0; i < 9; i++) actw[i] = a[i]*inv;
    }
}

// ---------------- GEMM (BT): C(MxN) = A(MxK) @ Bt(NxK)^T, 128x128 tile, BK=32 ----------------
// Pure bf16: both tiles staged with 16B loads + ds_write_b128 (validated sA pattern).
// MODE 0: outH = bf16(acc+bias)     MODE 1: outH = bf16(tanh(acc+bias))
// MODE 2: outF = acc+bias           MODE 3: outF = acc
// MODE 4: hidden epilogue (gate contraction over n, qact, mask) -> bf16
template <int MODE>
__global__ __launch_bounds__(256, 2) void gemm_bt(
        const bf16* __restrict__ A, const bf16* __restrict__ Bt,
        int K,
        const float* __restrict__ bias,
        float* __restrict__ outF, bf16* __restrict__ outH,
        const float* __restrict__ gate, const float* __restrict__ actw,
        const float* __restrict__ mask, int outStride) {
    __shared__ __align__(16) short sA[128*32];
    __shared__ __align__(16) short sB[128*32];
    int t = threadIdx.x, lane = t & 63;
    int rowBase = blockIdx.y * 128, colBase = blockIdx.x * 128;
    int lm = lane & 15, lq = lane >> 4;
    int w = t >> 6;
    int qm = (w >> 1) * 64, qn = (w & 1) * 64;

    f32x4 acc[4][4];
    #pragma unroll
    for (int i = 0; i < 4; i++)
        #pragma unroll
        for (int j = 0; j < 4; j++) acc[i][j] = (f32x4){0.f, 0.f, 0.f, 0.f};

    int ar = t >> 2, ak = (t & 3) * 8;

    for (int k0 = 0; k0 < K; k0 += 32) {
        __syncthreads();
        *reinterpret_cast<s16x8*>(sA + ar*32 + ak) =
            *reinterpret_cast<const s16x8*>(A + (size_t)(rowBase + ar)*K + k0 + ak);
        *reinterpret_cast<s16x8*>(sA + (ar + 64)*32 + ak) =
            *reinterpret_cast<const s16x8*>(A + (size_t)(rowBase + ar + 64)*K + k0 + ak);
        *reinterpret_cast<s16x8*>(sB + ar*32 + ak) =
            *reinterpret_cast<const s16x8*>(Bt + (size_t)(colBase + ar)*K + k0 + ak);
        *reinterpret_cast<s16x8*>(sB + (ar + 64)*32 + ak) =
            *reinterpret_cast<const s16x8*>(Bt + (size_t)(colBase + ar + 64)*K + k0 + ak);
        __syncthreads();
        s16x8 af[4], bfr[4];
        #pragma unroll
        for (int mi = 0; mi < 4; mi++)
            af[mi] = *reinterpret_cast<const s16x8*>(sA + (qm + mi*16 + lm)*32 + lq*8);
        #pragma unroll
        for (int ni = 0; ni < 4; ni++)
            bfr[ni] = *reinterpret_cast<const s16x8*>(sB + (qn + ni*16 + lm)*32 + lq*8);
        #pragma unroll
        for (int mi = 0; mi < 4; mi++)
            #pragma unroll
            for (int ni = 0; ni < 4; ni++)
                acc[mi][ni] = __builtin_amdgcn_mfma_f32_16x16x32_bf16(af[mi], bfr[ni], acc[mi][ni], 0, 0, 0);
    }

    if (MODE == 4) {
        float aw[9];
        #pragma unroll
        for (int i = 0; i < 9; i++) aw[i] = actw[i];
        #pragma unroll
        for (int mi = 0; mi < 4; mi++) {
            int row0 = rowBase + qm + mi*16 + lq*4;
            #pragma unroll
            for (int ni = 0; ni < 4; ni++) {
                int col = colBase + qn + ni*16 + lm;
                int n = col & 3;
                float bb = bias[col];
                f32x4 v = acc[mi][ni];
                #pragma unroll
                for (int r = 0; r < 4; r++) v[r] = (v[r] + bb) * gate[(row0 + r)*4 + n];
                #pragma unroll
                for (int r = 0; r < 4; r++) v[r] += __shfl_xor(v[r], 1);
                #pragma unroll
                for (int r = 0; r < 4; r++) v[r] += __shfl_xor(v[r], 2);
                if ((lane & 3) == 0) {
                    int uu = col >> 2;
                    float mk = mask[uu];
                    #pragma unroll
                    for (int r = 0; r < 4; r++)
                        outH[(size_t)(row0 + r)*outStride + uu] = __float2bfloat16(qact(v[r], aw) * mk);
                }
            }
        }
    } else {
        #pragma unroll
        for (int mi = 0; mi < 4; mi++) {
            int row0 = rowBase + qm + mi*16 + lq*4;
            #pragma unroll
            for (int ni = 0; ni < 4; ni++) {
                int col = colBase + qn + ni*16 + lm;
                float bb = (MODE == 3) ? 0.f : bias[col];
                #pragma unroll
                for (int r = 0; r < 4; r++) {
                    float vv = acc[mi][ni][r] + bb;
                    size_t oi = (size_t)(row0 + r)*outStride + col;
                    if (MODE == 0) outH[oi] = __float2bfloat16(vv);
                    if (MODE == 1) outH[oi] = __float2bfloat16(tanhf(vv));
                    if (MODE == 2 || MODE == 3) outF[oi] = vv;
                }
            }
        }
    }
}

// ---------------- in-place row softmax over 2048 cols (bf16 buffer) ----------------
__global__ __launch_bounds__(256) void k_softmax(bf16* __restrict__ ratt) {
    int b = blockIdx.x, t = threadIdx.x, w = t >> 6, lane = t & 63;
    __shared__ float red[8];
    bf16* row = ratt + (size_t)b*2048;
    float v[8];
    float mx = -1e30f;
    #pragma unroll
    for (int j = 0; j < 8; j++) {
        v[j] = __bfloat162float(row[t + j*256]);
        mx = fmaxf(mx, v[j]);
    }
    #pragma unroll
    for (int off = 32; off; off >>= 1) mx = fmaxf(mx, __shfl_xor(mx, off));
    if (lane == 0) red[w] = mx;
    __syncthreads();
    mx = fmaxf(fmaxf(red[0], red[1]), fmaxf(red[2], red[3]));
    float s = 0.f;
    #pragma unroll
    for (int j = 0; j < 8; j++) { v[j] = __expf(v[j] - mx); s += v[j]; }
    #pragma unroll
    for (int off = 32; off; off >>= 1) s += __shfl_xor(s, off);
    if (lane == 0) red[4 + w] = s;
    __syncthreads();
    float inv = 1.f / (red[4] + red[5] + red[6] + red[7]);
    #pragma unroll
    for (int j = 0; j < 8; j++)
        row[t + j*256] = __float2bfloat16(v[j] * inv);
}

// ---------------- column-mean partials ----------------
__global__ __launch_bounds__(256) void k_colpart(const bf16* __restrict__ ratt,
                                                 const bf16* __restrict__ cand,
                                                 float* __restrict__ part) {
    int ct = blockIdx.x, rc = blockIdx.y, t = threadIdx.x;
    int col = ct*256 + t;
    const bf16* src; int stride, c;
    if (ct < 8) { src = ratt; stride = 2048; c = col; }
    else        { src = cand; stride = 1024; c = col - 2048; }
    float s = 0.f;
    int r0 = rc*128;
    for (int r = 0; r < 128; r++)
        s += __bfloat162float(src[(size_t)(r0 + r)*stride + c]);
    part[rc*3072 + col] = s;
}

__global__ __launch_bounds__(256) void k_colfin(const float* __restrict__ part,
                                                const float* __restrict__ update_gate,
                                                float* __restrict__ u,
                                                float* __restrict__ cmean) {
    int col = blockIdx.x*256 + threadIdx.x;
    float s = 0.f;
    #pragma unroll
    for (int rc = 0; rc < 8; rc++) s += part[rc*3072 + col];
    s *= (1.f/1024.f);
    if (col < 2048) u[col] = s * update_gate[col];
    else            cmean[col - 2048] = s;
}

// ---------------- new_mem blend (f32 out) ----------------
__global__ __launch_bounds__(256) void k_newmem(const float* __restrict__ mem,
                                                const float* __restrict__ u,
                                                const float* __restrict__ cmean,
                                                float* __restrict__ out1) {
    int idx = blockIdx.x*256 + threadIdx.x;
    int m = idx >> 10, d = idx & 1023;
    float um = u[m];
    out1[idx] = mem[idx] * (1.f - um) + um * cmean[d];
}

// ---------------- critic + final gating: 1 batch row per block, LDS-staged ----------------
__global__ __launch_bounds__(256) void k_critic(
        const float* __restrict__ readv, const float* __restrict__ preds,
        const bf16* __restrict__ hidden,
        const float* cw1, const float* cb1, const float* cw2, const float* cb2,
        const float* cw3, const float* cb3, const float* cw4, const float* cb4,
        const float* cw5, const float* cb5, const float* thr,
        float* __restrict__ out0) {
    __shared__ __align__(16) float sx[1024];
    __shared__ __align__(16) float sp[512];
    __shared__ __align__(16) short sh[2048];
    __shared__ float part[8][32];
    __shared__ float feat[96];
    __shared__ float fused[64];
    __shared__ float gsh;
    int b = blockIdx.x, t = threadIdx.x;
    int j = t & 31, g = t >> 5;

    ((f32x4*)sx)[t] = ((const f32x4*)(readv + (size_t)b*1024))[t];
    if (t < 128) ((f32x4*)sp)[t] = ((const f32x4*)(preds + (size_t)b*512))[t];
    ((s16x8*)sh)[t] = ((const s16x8*)(hidden + (size_t)b*2048))[t];
    __syncthreads();

    {
        float a = 0.f;
        int k0 = g*128;
        #pragma unroll 4
        for (int k = k0; k < k0 + 128; k++) a += sx[k] * cw1[k*32 + j];
        part[g][j] = a;
    }
    __syncthreads();
    if (t < 32) {
        float s = 0.f;
        #pragma unroll
        for (int i = 0; i < 8; i++) s += part[i][t];
        feat[t] = fmaxf(s + cb1[t], 0.f);
    }
    __syncthreads();
    {
        float a = 0.f;
        int k0 = g*64;
        #pragma unroll 4
        for (int k = k0; k < k0 + 64; k++) a += sp[k] * cw2[k*32 + j];
        part[g][j] = a;
    }
    __syncthreads();
    if (t < 32) {
        float s = 0.f;
        #pragma unroll
        for (int i = 0; i < 8; i++) s += part[i][t];
        feat[32 + t] = fmaxf(s + cb2[t], 0.f);
    }
    __syncthreads();
    {
        float a = 0.f;
        int k0 = g*256;
        #pragma unroll 4
        for (int k = k0; k < k0 + 256; k++) {
            bf16 hv = *reinterpret_cast<const bf16*>(&sh[k]);
            a += __bfloat162float(hv) * cw3[k*32 + j];
        }
        part[g][j] = a;
    }
    __syncthreads();
    if (t < 32) {
        float s = 0.f;
        #pragma unroll
        for (int i = 0; i < 8; i++) s += part[i][t];
        feat[64 + t] = fmaxf(s + cb3[t], 0.f);
    }
    __syncthreads();
    if (t < 64) {
        float s = 0.f;
        #pragma unroll 8
        for (int k = 0; k < 96; k++) s += feat[k] * cw4[k*64 + t];
        fused[t] = fmaxf(s + cb4[t], 0.f);
    }
    __syncthreads();
    if (t < 64) {
        float v = fused[t] * cw5[t*2];
        #pragma unroll
        for (int off = 32; off; off >>= 1) v += __shfl_xor(v, off);
        if (t == 0)
            gsh = 1.f / (1.f + __expf(-(v + cb5[0] - thr[0])));
    }
    __syncthreads();
    float gg = gsh;
    #pragma unroll
    for (int o = t; o < 512; o += 256)
        out0[(size_t)b*512 + o] = sp[o] * gg;
}

extern "C" void kernel_launch(void* const* d_in, const int* in_sizes, int n_in,
                              void* d_out, int out_size, void* d_ws, size_t ws_size,
                              hipStream_t stream) {
    const float* x        = (const float*)d_in[0];
    const float* w_       = (const float*)d_in[1];   // (1024, 8192)
    const float* b_bias   = (const float*)d_in[2];
    const float* gate_w   = (const float*)d_in[3];
    const float* gate_b   = (const float*)d_in[4];
    const float* act_w    = (const float*)d_in[5];
    const float* mask     = (const float*)d_in[6];
    const float* mem      = (const float*)d_in[7];   // (2048, 1024)
    const float* att_w    = (const float*)d_in[8];   // (2048, 2048)
    const float* att_b    = (const float*)d_in[9];
    const float* write_w  = (const float*)d_in[10];  // (2048, 1024)
    const float* write_b  = (const float*)d_in[11];
    const float* upd_gate = (const float*)d_in[12];
    const float* out_w    = (const float*)d_in[13];  // (2048, 512)
    const float* out_b    = (const float*)d_in[14];
    const float* cw1 = (const float*)d_in[15]; const float* cb1 = (const float*)d_in[16];
    const float* cw2 = (const float*)d_in[17]; const float* cb2 = (const float*)d_in[18];
    const float* cw3 = (const float*)d_in[19]; const float* cb3 = (const float*)d_in[20];
    const float* cw4 = (const float*)d_in[21]; const float* cb4 = (const float*)d_in[22];
    const float* cw5 = (const float*)d_in[23]; const float* cb5 = (const float*)d_in[24];
    const float* thr = (const float*)d_in[25];

    char* ws = (char*)d_ws;
    float* gate   = (float*)(ws + GATE_OFF);
    float* actw   = (float*)(ws + ACTW_OFF);
    float* uvec   = (float*)(ws + U_OFF);
    float* cmean  = (float*)(ws + CMEAN_OFF);
    float* part   = (float*)(ws + PART_OFF);
    bf16*  hidden = (bf16*)(ws + HIDDEN_OFF);
    bf16*  ratt   = (bf16*)(ws + RATT_OFF);
    bf16*  cand   = (bf16*)(ws + CAND_OFF);
    float* preds  = (float*)(ws + PREDS_OFF);
    float* readv  = (float*)(ws + READ_OFF);
    bf16*  xbf    = (bf16*)(ws + XBF_OFF);
    bf16*  wT     = (bf16*)(ws + WT_OFF);
    bf16*  attwT  = (bf16*)(ws + ATTWT_OFF);
    bf16*  writewT= (bf16*)(ws + WRITEWT_OFF);
    bf16*  outwT  = (bf16*)(ws + OUTWT_OFF);
    bf16*  memT   = (bf16*)(ws + MEMT_OFF);

    float* out0 = (float*)d_out;            // (1024, 512)
    float* out1 = out0 + 1024*512;          // (2048, 1024)

    dim3 tb(64, 4);
    // prepass: convert + transpose weights to bf16 N x K
    k_cvt<<<1024, 256, 0, stream>>>(x, xbf);
    k_transpose<<<dim3(128, 16), tb, 0, stream>>>(w_,      wT,      1024, 8192);
    k_transpose<<<dim3(32, 32),  tb, 0, stream>>>(att_w,   attwT,   2048, 2048);
    k_transpose<<<dim3(16, 32),  tb, 0, stream>>>(write_w, writewT, 2048, 1024);
    k_transpose<<<dim3(8, 32),   tb, 0, stream>>>(out_w,   outwT,   2048, 512);
    k_transpose<<<dim3(16, 32),  tb, 0, stream>>>(mem,     memT,    2048, 1024);

    k_gate<<<1024, 256, 0, stream>>>(x, gate_w, gate_b, act_w, gate, actw);

    // hidden = qact((x@w + b)·gate) * mask        [M=1024, N=8192, K=1024]
    gemm_bt<4><<<dim3(64, 8), 256, 0, stream>>>(xbf, wT, 1024,
        b_bias, nullptr, hidden, gate, actw, mask, 2048);
    // att logits = hidden @ att_w + att_b         [M=1024, N=2048, K=2048]
    gemm_bt<0><<<dim3(16, 8), 256, 0, stream>>>(hidden, attwT, 2048,
        att_b, nullptr, ratt, nullptr, nullptr, nullptr, 2048);
    k_softmax<<<1024, 256, 0, stream>>>(ratt);
    // cand = tanh(hidden @ write_w + write_b)     [M=1024, N=1024, K=2048]
    gemm_bt<1><<<dim3(8, 8), 256, 0, stream>>>(hidden, writewT, 2048,
        write_b, nullptr, cand, nullptr, nullptr, nullptr, 1024);
    // preds = hidden @ out_w + out_b (f32)        [M=1024, N=512, K=2048]
    gemm_bt<2><<<dim3(4, 8), 256, 0, stream>>>(hidden, outwT, 2048,
        out_b, preds, nullptr, nullptr, nullptr, nullptr, 512);
    // read = ratt @ mem (f32)                     [M=1024, N=1024, K=2048]
    gemm_bt<3><<<dim3(8, 8), 256, 0, stream>>>(ratt, memT, 2048,
        nullptr, readv, nullptr, nullptr, nullptr, nullptr, 1024);

    k_colpart<<<dim3(12, 8), 256, 0, stream>>>(ratt, cand, part);
    k_colfin<<<12, 256, 0, stream>>>(part, upd_gate, uvec, cmean);
    k_newmem<<<8192, 256, 0, stream>>>(mem, uvec, cmean, out1);
    k_critic<<<1024, 256, 0, stream>>>(readv, preds, hidden,
        cw1, cb1, cw2, cb2, cw3, cb3, cw4, cb4, cw5, cb5, thr, out0);
}

// Round 8
// 412.163 us; speedup vs baseline: 1.5832x; 1.1967x over previous
//
#include <hip/hip_runtime.h>
#include <hip/hip_bf16.h>
#include <math.h>

typedef __attribute__((ext_vector_type(4))) float f32x4;
typedef __attribute__((ext_vector_type(8))) short s16x8;
typedef __attribute__((ext_vector_type(4))) short s16x4;
typedef __hip_bfloat16 bf16;

#define MB (1024ull*1024ull)
// workspace layout (bytes) — total 53 MB
#define GATE_OFF    (0ull)          // 1024*4 f32
#define ACTW_OFF    (16ull*1024)    // 9 f32
#define U_OFF       (20ull*1024)    // 2048 f32
#define CMEAN_OFF   (28ull*1024)    // 1024 f32
#define PART_OFF    (64ull*1024)    // 8*3072 f32
#define HIDDEN_OFF  (1ull*MB)       // bf16 1024x2048 (4MB)
#define RATT_OFF    (5ull*MB)       // bf16 1024x2048 (4MB)
#define CAND_OFF    (9ull*MB)       // bf16 1024x1024 (2MB)
#define PREDS_OFF   (11ull*MB)      // f32 1024x512  (2MB)
#define READ_OFF    (13ull*MB)      // f32 1024x1024 (4MB)
#define XBF_OFF     (17ull*MB)      // bf16 1024x1024 (2MB)
#define WT_OFF      (19ull*MB)      // bf16 8192x1024 (16MB) -> ends 35
#define CATT_OFF    (35ull*MB)      // bf16 3584x2048 (14MB) -> ends 49  [att|write|out]^T
#define MEMT_OFF    (49ull*MB)      // bf16 1024x2048 (4MB) -> ends 53

__device__ __forceinline__ short f2bf_s(float f) {
    bf16 h = __float2bfloat16(f);
    return *reinterpret_cast<short*>(&h);
}

__device__ __forceinline__ void async_load16(const bf16* g, short* l) {
    __builtin_amdgcn_global_load_lds((const __attribute__((address_space(1))) void*)g,
                                     (__attribute__((address_space(3))) void*)l, 16, 0, 0);
}

__device__ __forceinline__ float qact(float x, const float* w) {
    float ex  = __expf(x);
    float sig = 1.f / (1.f + __expf(-x));
    float elu = x > 0.f ? x : ex - 1.f;
    float th  = tanhf(x);
    float rel = fmaxf(x, 0.f);
    float silu = x * sig;
    float gel = 0.5f * x * (1.f + erff(x * 0.70710678118654752f));
    float sel = 1.0507009873554805f * (x > 0.f ? x : 1.6732632423543772f * (ex - 1.f));
    float sp  = (x > 15.f) ? x : log1pf(ex);
    float mish = x * tanhf(sp);
    return w[0]*sig + w[1]*elu + w[2]*th + w[3]*rel + w[4]*silu
         + w[5]*gel + w[6]*sel + w[7]*mish + w[8]*x;
}

// ---------------- fp32 (R x C) -> bf16 (C x R) transpose, 64x64 tiles ----------------
__global__ __launch_bounds__(256) void k_transpose(const float* __restrict__ in,
                                                   bf16* __restrict__ out, int R, int C) {
    __shared__ short tile[64][66];
    int k0 = blockIdx.y*64, n0 = blockIdx.x*64;
    int tx = threadIdx.x, ty = threadIdx.y;     // (64,4)
    #pragma unroll
    for (int j = 0; j < 16; j++) {
        int k = ty + j*4;
        tile[tx][k] = f2bf_s(in[(size_t)(k0 + k)*C + n0 + tx]);
    }
    __syncthreads();
    int t = ty*64 + tx;
    int kp = t & 31, nrow = t >> 5;
    #pragma unroll
    for (int jj = 0; jj < 8; jj++) {
        int n = nrow + jj*8;
        unsigned lo = (unsigned short)tile[n][kp*2];
        unsigned hi = (unsigned short)tile[n][kp*2 + 1];
        *reinterpret_cast<unsigned*>(&out[(size_t)(n0 + n)*R + k0 + kp*2]) = lo | (hi << 16);
    }
}

// ---------------- fp32 -> bf16 flat convert ----------------
__global__ __launch_bounds__(256) void k_cvt(const float* __restrict__ in,
                                             bf16* __restrict__ out) {
    int i = blockIdx.x*256 + threadIdx.x;
    f32x4 v = ((const f32x4*)in)[i];
    s16x4 o;
    #pragma unroll
    for (int j = 0; j < 4; j++) o[j] = f2bf_s(v[j]);
    ((s16x4*)out)[i] = o;
}

// ---------------- gate softmax + act-weight softmax (all f32) ----------------
__global__ __launch_bounds__(256) void k_gate(const float* __restrict__ x,
                                              const float* __restrict__ gw,
                                              const float* __restrict__ gb,
                                              const float* __restrict__ aw_in,
                                              float* __restrict__ gate,
                                              float* __restrict__ actw) {
    int b = blockIdx.x, t = threadIdx.x, w = t >> 6, lane = t & 63;
    __shared__ float l[4];
    float s = 0.f;
    for (int k = lane; k < 1024; k += 64)
        s += x[(size_t)b*1024 + k] * gw[k*4 + w];
    #pragma unroll
    for (int off = 32; off; off >>= 1) s += __shfl_xor(s, off);
    if (lane == 0) l[w] = s + gb[w];
    __syncthreads();
    if (t == 0) {
        float m = fmaxf(fmaxf(l[0], l[1]), fmaxf(l[2], l[3]));
        float e0 = __expf(l[0]-m), e1 = __expf(l[1]-m), e2 = __expf(l[2]-m), e3 = __expf(l[3]-m);
        float inv = 1.f / (e0+e1+e2+e3);
        gate[b*4+0] = e0*inv; gate[b*4+1] = e1*inv;
        gate[b*4+2] = e2*inv; gate[b*4+3] = e3*inv;
    }
    if (b == 0 && t == 64) {
        float a[9]; float m = -1e30f;
        for (int i = 0; i < 9; i++) { a[i] = aw_in[i]; m = fmaxf(m, a[i]); }
        float ss = 0.f;
        for (int i = 0; i < 9; i++) { a[i] = __expf(a[i]-m); ss += a[i]; }
        float inv = 1.f / ss;
        for (int i = 0; i < 9; i++) actw[i] = a[i]*inv;
    }
}

// ---------------- GEMM (BT): C(MxN) = A(MxK) @ Bt(NxK)^T, 128x128 tile, BK=32 ----------------
// global_load_lds width-16 staging (m97 structure): LDS dst = wave-uniform base + lane*16.
// MODE 3: outF = acc                                   [read]
// MODE 4: hidden epilogue (gate contraction, qact, mask) -> bf16
// MODE 5: fused 3-head epilogue: col<2048 ratt logits (bf16), <3072 cand=tanh (bf16), else preds (f32)
template <int MODE>
__global__ __launch_bounds__(256, 2) void gemm_bt(
        const bf16* __restrict__ A, const bf16* __restrict__ Bt,
        int K,
        const float* __restrict__ bias, const float* __restrict__ bias2,
        const float* __restrict__ bias3,
        float* __restrict__ outF, bf16* __restrict__ outH, bf16* __restrict__ outH2,
        const float* __restrict__ gate, const float* __restrict__ actw,
        const float* __restrict__ mask, int outStride) {
    __shared__ __align__(16) short sA[128*32];
    __shared__ __align__(16) short sB[128*32];
    int t = threadIdx.x, lane = t & 63;
    int rowBase = blockIdx.y * 128, colBase = blockIdx.x * 128;
    int lm = lane & 15, lq = lane >> 4;
    int w = t >> 6;
    int qm = (w >> 1) * 64, qn = (w & 1) * 64;

    f32x4 acc[4][4];
    #pragma unroll
    for (int i = 0; i < 4; i++)
        #pragma unroll
        for (int j = 0; j < 4; j++) acc[i][j] = (f32x4){0.f, 0.f, 0.f, 0.f};

    // async staging map: chunk c = w*128 + lane (+64); row = c>>2, kofs = (c&3)*8
    int c0 = w*128 + lane, c1 = c0 + 64;
    int r0 = c0 >> 2, ko0 = (c0 & 3) * 8;
    int r1 = c1 >> 2, ko1 = (c1 & 3) * 8;
    short* dstA0 = sA + w*1024;          // chunk base w*128 (16B chunks)
    short* dstA1 = sA + w*1024 + 512;
    short* dstB0 = sB + w*1024;
    short* dstB1 = sB + w*1024 + 512;

    for (int k0 = 0; k0 < K; k0 += 32) {
        __syncthreads();
        async_load16(A  + (size_t)(rowBase + r0)*K + k0 + ko0, dstA0);
        async_load16(A  + (size_t)(rowBase + r1)*K + k0 + ko1, dstA1);
        async_load16(Bt + (size_t)(colBase + r0)*K + k0 + ko0, dstB0);
        async_load16(Bt + (size_t)(colBase + r1)*K + k0 + ko1, dstB1);
        __syncthreads();   // compiler drains vmcnt before s_barrier
        s16x8 af[4], bfr[4];
        #pragma unroll
        for (int mi = 0; mi < 4; mi++)
            af[mi] = *reinterpret_cast<const s16x8*>(sA + (qm + mi*16 + lm)*32 + lq*8);
        #pragma unroll
        for (int ni = 0; ni < 4; ni++)
            bfr[ni] = *reinterpret_cast<const s16x8*>(sB + (qn + ni*16 + lm)*32 + lq*8);
        #pragma unroll
        for (int mi = 0; mi < 4; mi++)
            #pragma unroll
            for (int ni = 0; ni < 4; ni++)
                acc[mi][ni] = __builtin_amdgcn_mfma_f32_16x16x32_bf16(af[mi], bfr[ni], acc[mi][ni], 0, 0, 0);
    }

    if (MODE == 4) {
        float aw[9];
        #pragma unroll
        for (int i = 0; i < 9; i++) aw[i] = actw[i];
        #pragma unroll
        for (int mi = 0; mi < 4; mi++) {
            int row0 = rowBase + qm + mi*16 + lq*4;
            #pragma unroll
            for (int ni = 0; ni < 4; ni++) {
                int col = colBase + qn + ni*16 + lm;
                int n = col & 3;
                float bb = bias[col];
                f32x4 v = acc[mi][ni];
                #pragma unroll
                for (int r = 0; r < 4; r++) v[r] = (v[r] + bb) * gate[(row0 + r)*4 + n];
                #pragma unroll
                for (int r = 0; r < 4; r++) v[r] += __shfl_xor(v[r], 1);
                #pragma unroll
                for (int r = 0; r < 4; r++) v[r] += __shfl_xor(v[r], 2);
                if ((lane & 3) == 0) {
                    int uu = col >> 2;
                    float mk = mask[uu];
                    #pragma unroll
                    for (int r = 0; r < 4; r++)
                        outH[(size_t)(row0 + r)*outStride + uu] = __float2bfloat16(qact(v[r], aw) * mk);
                }
            }
        }
    } else if (MODE == 5) {
        #pragma unroll
        for (int mi = 0; mi < 4; mi++) {
            int row0 = rowBase + qm + mi*16 + lq*4;
            #pragma unroll
            for (int ni = 0; ni < 4; ni++) {
                int col = colBase + qn + ni*16 + lm;
                if (col < 2048) {
                    float bb = bias[col];
                    #pragma unroll
                    for (int r = 0; r < 4; r++)
                        outH[(size_t)(row0 + r)*2048 + col] = __float2bfloat16(acc[mi][ni][r] + bb);
                } else if (col < 3072) {
                    int c = col - 2048;
                    float bb = bias2[c];
                    #pragma unroll
                    for (int r = 0; r < 4; r++)
                        outH2[(size_t)(row0 + r)*1024 + c] = __float2bfloat16(tanhf(acc[mi][ni][r] + bb));
                } else {
                    int c = col - 3072;
                    float bb = bias3[c];
                    #pragma unroll
                    for (int r = 0; r < 4; r++)
                        outF[(size_t)(row0 + r)*512 + c] = acc[mi][ni][r] + bb;
                }
            }
        }
    } else {  // MODE 3
        #pragma unroll
        for (int mi = 0; mi < 4; mi++) {
            int row0 = rowBase + qm + mi*16 + lq*4;
            #pragma unroll
            for (int ni = 0; ni < 4; ni++) {
                int col = colBase + qn + ni*16 + lm;
                #pragma unroll
                for (int r = 0; r < 4; r++)
                    outF[(size_t)(row0 + r)*outStride + col] = acc[mi][ni][r];
            }
        }
    }
}

// ---------------- in-place row softmax over 2048 cols (bf16 buffer) ----------------
__global__ __launch_bounds__(256) void k_softmax(bf16* __restrict__ ratt) {
    int b = blockIdx.x, t = threadIdx.x, w = t >> 6, lane = t & 63;
    __shared__ float red[8];
    bf16* row = ratt + (size_t)b*2048;
    float v[8];
    float mx = -1e30f;
    #pragma unroll
    for (int j = 0; j < 8; j++) {
        v[j] = __bfloat162float(row[t + j*256]);
        mx = fmaxf(mx, v[j]);
    }
    #pragma unroll
    for (int off = 32; off; off >>= 1) mx = fmaxf(mx, __shfl_xor(mx, off));
    if (lane == 0) red[w] = mx;
    __syncthreads();
    mx = fmaxf(fmaxf(red[0], red[1]), fmaxf(red[2], red[3]));
    float s = 0.f;
    #pragma unroll
    for (int j = 0; j < 8; j++) { v[j] = __expf(v[j] - mx); s += v[j]; }
    #pragma unroll
    for (int off = 32; off; off >>= 1) s += __shfl_xor(s, off);
    if (lane == 0) red[4 + w] = s;
    __syncthreads();
    float inv = 1.f / (red[4] + red[5] + red[6] + red[7]);
    #pragma unroll
    for (int j = 0; j < 8; j++)
        row[t + j*256] = __float2bfloat16(v[j] * inv);
}

// ---------------- column-mean partials ----------------
__global__ __launch_bounds__(256) void k_colpart(const bf16* __restrict__ ratt,
                                                 const bf16* __restrict__ cand,
                                                 float* __restrict__ part) {
    int ct = blockIdx.x, rc = blockIdx.y, t = threadIdx.x;
    int col = ct*256 + t;
    const bf16* src; int stride, c;
    if (ct < 8) { src = ratt; stride = 2048; c = col; }
    else        { src = cand; stride = 1024; c = col - 2048; }
    float s = 0.f;
    int r0 = rc*128;
    for (int r = 0; r < 128; r++)
        s += __bfloat162float(src[(size_t)(r0 + r)*stride + c]);
    part[rc*3072 + col] = s;
}

__global__ __launch_bounds__(256) void k_colfin(const float* __restrict__ part,
                                                const float* __restrict__ update_gate,
                                                float* __restrict__ u,
                                                float* __restrict__ cmean) {
    int col = blockIdx.x*256 + threadIdx.x;
    float s = 0.f;
    #pragma unroll
    for (int rc = 0; rc < 8; rc++) s += part[rc*3072 + col];
    s *= (1.f/1024.f);
    if (col < 2048) u[col] = s * update_gate[col];
    else            cmean[col - 2048] = s;
}

// ---------------- new_mem blend (f32 out) ----------------
__global__ __launch_bounds__(256) void k_newmem(const float* __restrict__ mem,
                                                const float* __restrict__ u,
                                                const float* __restrict__ cmean,
                                                float* __restrict__ out1) {
    int idx = blockIdx.x*256 + threadIdx.x;
    int m = idx >> 10, d = idx & 1023;
    float um = u[m];
    out1[idx] = mem[idx] * (1.f - um) + um * cmean[d];
}

// ---------------- critic + final gating: 1 batch row per block, LDS-staged ----------------
__global__ __launch_bounds__(256) void k_critic(
        const float* __restrict__ readv, const float* __restrict__ preds,
        const bf16* __restrict__ hidden,
        const float* cw1, const float* cb1, const float* cw2, const float* cb2,
        const float* cw3, const float* cb3, const float* cw4, const float* cb4,
        const float* cw5, const float* cb5, const float* thr,
        float* __restrict__ out0) {
    __shared__ __align__(16) float sx[1024];
    __shared__ __align__(16) float sp[512];
    __shared__ __align__(16) short sh[2048];
    __shared__ float part[8][32];
    __shared__ float feat[96];
    __shared__ float fused[64];
    __shared__ float gsh;
    int b = blockIdx.x, t = threadIdx.x;
    int j = t & 31, g = t >> 5;

    ((f32x4*)sx)[t] = ((const f32x4*)(readv + (size_t)b*1024))[t];
    if (t < 128) ((f32x4*)sp)[t] = ((const f32x4*)(preds + (size_t)b*512))[t];
    ((s16x8*)sh)[t] = ((const s16x8*)(hidden + (size_t)b*2048))[t];
    __syncthreads();

    {
        float a = 0.f;
        int k0 = g*128;
        #pragma unroll 4
        for (int k = k0; k < k0 + 128; k++) a += sx[k] * cw1[k*32 + j];
        part[g][j] = a;
    }
    __syncthreads();
    if (t < 32) {
        float s = 0.f;
        #pragma unroll
        for (int i = 0; i < 8; i++) s += part[i][t];
        feat[t] = fmaxf(s + cb1[t], 0.f);
    }
    __syncthreads();
    {
        float a = 0.f;
        int k0 = g*64;
        #pragma unroll 4
        for (int k = k0; k < k0 + 64; k++) a += sp[k] * cw2[k*32 + j];
        part[g][j] = a;
    }
    __syncthreads();
    if (t < 32) {
        float s = 0.f;
        #pragma unroll
        for (int i = 0; i < 8; i++) s += part[i][t];
        feat[32 + t] = fmaxf(s + cb2[t], 0.f);
    }
    __syncthreads();
    {
        float a = 0.f;
        int k0 = g*256;
        #pragma unroll 4
        for (int k = k0; k < k0 + 256; k++) {
            bf16 hv = *reinterpret_cast<const bf16*>(&sh[k]);
            a += __bfloat162float(hv) * cw3[k*32 + j];
        }
        part[g][j] = a;
    }
    __syncthreads();
    if (t < 32) {
        float s = 0.f;
        #pragma unroll
        for (int i = 0; i < 8; i++) s += part[i][t];
        feat[64 + t] = fmaxf(s + cb3[t], 0.f);
    }
    __syncthreads();
    if (t < 64) {
        float s = 0.f;
        #pragma unroll 8
        for (int k = 0; k < 96; k++) s += feat[k] * cw4[k*64 + t];
        fused[t] = fmaxf(s + cb4[t], 0.f);
    }
    __syncthreads();
    if (t < 64) {
        float v = fused[t] * cw5[t*2];
        #pragma unroll
        for (int off = 32; off; off >>= 1) v += __shfl_xor(v, off);
        if (t == 0)
            gsh = 1.f / (1.f + __expf(-(v + cb5[0] - thr[0])));
    }
    __syncthreads();
    float gg = gsh;
    #pragma unroll
    for (int o = t; o < 512; o += 256)
        out0[(size_t)b*512 + o] = sp[o] * gg;
}

extern "C" void kernel_launch(void* const* d_in, const int* in_sizes, int n_in,
                              void* d_out, int out_size, void* d_ws, size_t ws_size,
                              hipStream_t stream) {
    const float* x        = (const float*)d_in[0];
    const float* w_       = (const float*)d_in[1];   // (1024, 8192)
    const float* b_bias   = (const float*)d_in[2];
    const float* gate_w   = (const float*)d_in[3];
    const float* gate_b   = (const float*)d_in[4];
    const float* act_w    = (const float*)d_in[5];
    const float* mask     = (const float*)d_in[6];
    const float* mem      = (const float*)d_in[7];   // (2048, 1024)
    const float* att_w    = (const float*)d_in[8];   // (2048, 2048)
    const float* att_b    = (const float*)d_in[9];
    const float* write_w  = (const float*)d_in[10];  // (2048, 1024)
    const float* write_b  = (const float*)d_in[11];
    const float* upd_gate = (const float*)d_in[12];
    const float* out_w    = (const float*)d_in[13];  // (2048, 512)
    const float* out_b    = (const float*)d_in[14];
    const float* cw1 = (const float*)d_in[15]; const float* cb1 = (const float*)d_in[16];
    const float* cw2 = (const float*)d_in[17]; const float* cb2 = (const float*)d_in[18];
    const float* cw3 = (const float*)d_in[19]; const float* cb3 = (const float*)d_in[20];
    const float* cw4 = (const float*)d_in[21]; const float* cb4 = (const float*)d_in[22];
    const float* cw5 = (const float*)d_in[23]; const float* cb5 = (const float*)d_in[24];
    const float* thr = (const float*)d_in[25];

    char* ws = (char*)d_ws;
    float* gate   = (float*)(ws + GATE_OFF);
    float* actw   = (float*)(ws + ACTW_OFF);
    float* uvec   = (float*)(ws + U_OFF);
    float* cmean  = (float*)(ws + CMEAN_OFF);
    float* part   = (float*)(ws + PART_OFF);
    bf16*  hidden = (bf16*)(ws + HIDDEN_OFF);
    bf16*  ratt   = (bf16*)(ws + RATT_OFF);
    bf16*  cand   = (bf16*)(ws + CAND_OFF);
    float* preds  = (float*)(ws + PREDS_OFF);
    float* readv  = (float*)(ws + READ_OFF);
    bf16*  xbf    = (bf16*)(ws + XBF_OFF);
    bf16*  wT     = (bf16*)(ws + WT_OFF);
    bf16*  catT   = (bf16*)(ws + CATT_OFF);
    bf16*  memT   = (bf16*)(ws + MEMT_OFF);

    float* out0 = (float*)d_out;            // (1024, 512)
    float* out1 = out0 + 1024*512;          // (2048, 1024)

    dim3 tb(64, 4);
    // prepass: convert + transpose weights to bf16 N x K
    k_cvt<<<1024, 256, 0, stream>>>(x, xbf);
    k_transpose<<<dim3(128, 16), tb, 0, stream>>>(w_,      wT,             1024, 8192);
    k_transpose<<<dim3(32, 32),  tb, 0, stream>>>(att_w,   catT,           2048, 2048);
    k_transpose<<<dim3(16, 32),  tb, 0, stream>>>(write_w, catT + 2048ull*2048, 2048, 1024);
    k_transpose<<<dim3(8, 32),   tb, 0, stream>>>(out_w,   catT + 3072ull*2048, 2048, 512);
    k_transpose<<<dim3(16, 32),  tb, 0, stream>>>(mem,     memT,           2048, 1024);

    k_gate<<<1024, 256, 0, stream>>>(x, gate_w, gate_b, act_w, gate, actw);

    // G1: hidden = qact((x@w + b)·gate) * mask     [M=1024, N=8192, K=1024]
    gemm_bt<4><<<dim3(64, 8), 256, 0, stream>>>(xbf, wT, 1024,
        b_bias, nullptr, nullptr, nullptr, hidden, nullptr, gate, actw, mask, 2048);
    // G234 fused: [att|write|out] heads            [M=1024, N=3584, K=2048]
    gemm_bt<5><<<dim3(28, 8), 256, 0, stream>>>(hidden, catT, 2048,
        att_b, write_b, out_b, preds, ratt, cand, nullptr, nullptr, nullptr, 0);
    k_softmax<<<1024, 256, 0, stream>>>(ratt);
    // G5: read = ratt @ mem (f32)                  [M=1024, N=1024, K=2048]
    gemm_bt<3><<<dim3(8, 8), 256, 0, stream>>>(ratt, memT, 2048,
        nullptr, nullptr, nullptr, readv, nullptr, nullptr, nullptr, nullptr, nullptr, 1024);

    k_colpart<<<dim3(12, 8), 256, 0, stream>>>(ratt, cand, part);
    k_colfin<<<12, 256, 0, stream>>>(part, upd_gate, uvec, cmean);
    k_newmem<<<8192, 256, 0, stream>>>(mem, uvec, cmean, out1);
    k_critic<<<1024, 256, 0, stream>>>(readv, preds, hidden,
        cw1, cb1, cw2, cb2, cw3, cb3, cw4, cb4, cw5, cb5, thr, out0);
}

// Round 9
// 363.778 us; speedup vs baseline: 1.7938x; 1.1330x over previous
//
#include <hip/hip_runtime.h>
#include <hip/hip_bf16.h>
#include <math.h>

typedef __attribute__((ext_vector_type(4))) float f32x4;
typedef __attribute__((ext_vector_type(8))) short s16x8;
typedef __attribute__((ext_vector_type(4))) short s16x4;
typedef __hip_bfloat16 bf16;

#define MB (1024ull*1024ull)
// workspace layout (bytes) — total 53 MB
#define GATE_OFF    (0ull)          // 1024*4 f32
#define ACTW_OFF    (16ull*1024)    // 9 f32
#define U_OFF       (20ull*1024)    // 2048 f32
#define CMEAN_OFF   (28ull*1024)    // 1024 f32
#define PART_OFF    (64ull*1024)    // 8*3072 f32
#define HIDDEN_OFF  (1ull*MB)       // bf16 1024x2048 (4MB)
#define RATT_OFF    (5ull*MB)       // bf16 1024x2048 (4MB)
#define CAND_OFF    (9ull*MB)       // bf16 1024x1024 (2MB)
#define PREDS_OFF   (11ull*MB)      // f32 1024x512  (2MB)
#define READ_OFF    (13ull*MB)      // f32 1024x1024 (4MB)
#define XBF_OFF     (17ull*MB)      // bf16 1024x1024 (2MB)
#define WT_OFF      (19ull*MB)      // bf16 8192x1024 (16MB) -> ends 35
#define CATT_OFF    (35ull*MB)      // bf16 3584x2048 (14MB) -> ends 49  [att|write|out]^T
#define MEMT_OFF    (49ull*MB)      // bf16 1024x2048 (4MB) -> ends 53

__device__ __forceinline__ short f2bf_s(float f) {
    bf16 h = __float2bfloat16(f);
    return *reinterpret_cast<short*>(&h);
}

__device__ __forceinline__ void async_load16(const bf16* g, short* l) {
    __builtin_amdgcn_global_load_lds((const __attribute__((address_space(1))) void*)g,
                                     (__attribute__((address_space(3))) void*)l, 16, 0, 0);
}

// fast tanh: 1 - 2/(e^{2x}+1); inf-safe at both ends
__device__ __forceinline__ float fast_tanh(float x) {
    float e2x = __expf(2.f * x);
    return 1.f - 2.f / (e2x + 1.f);
}

// fast 9-way activation mix — __expf algebra only (no libm tanhf/erff/log1pf).
// gelu uses the tanh form (err ~1e-3, x w[5]~1/9 -> ~1e-4, << 1.05e-2 threshold).
__device__ __forceinline__ float qact(float x, const float* w) {
    float ex  = __expf(x);
    float r1  = 1.f / (1.f + ex);
    float sig = 1.f - r1;                       // sigmoid, inf-safe
    float em1 = ex - 1.f;
    float elu = x > 0.f ? x : em1;
    float e2x = ex * ex;
    float th  = 1.f - 2.f / (e2x + 1.f);        // tanh
    float rel = fmaxf(x, 0.f);
    float silu = x * sig;
    float u   = 0.7978845608028654f * (x + 0.044715f * x * x * x);
    float e2u = __expf(2.f * u);
    float gel = x * (1.f - 1.f / (e2u + 1.f));  // 0.5x(1+tanh(u))
    float sel = 1.0507009873554805f * (x > 0.f ? x : 1.6732632423543772f * em1);
    float t   = 1.f + ex;
    float t2  = t * t;
    float mish = x * (1.f - 2.f / (t2 + 1.f));  // x*tanh(softplus(x))
    return w[0]*sig + w[1]*elu + w[2]*th + w[3]*rel + w[4]*silu
         + w[5]*gel + w[6]*sel + w[7]*mish + w[8]*x;
}

// ---------------- fp32 (R x C) -> bf16 (C x R) transpose, 64x64 tiles ----------------
__global__ __launch_bounds__(256) void k_transpose(const float* __restrict__ in,
                                                   bf16* __restrict__ out, int R, int C) {
    __shared__ short tile[64][66];
    int k0 = blockIdx.y*64, n0 = blockIdx.x*64;
    int tx = threadIdx.x, ty = threadIdx.y;     // (64,4)
    #pragma unroll
    for (int j = 0; j < 16; j++) {
        int k = ty + j*4;
        tile[tx][k] = f2bf_s(in[(size_t)(k0 + k)*C + n0 + tx]);
    }
    __syncthreads();
    int t = ty*64 + tx;
    int kp = t & 31, nrow = t >> 5;
    #pragma unroll
    for (int jj = 0; jj < 8; jj++) {
        int n = nrow + jj*8;
        unsigned lo = (unsigned short)tile[n][kp*2];
        unsigned hi = (unsigned short)tile[n][kp*2 + 1];
        *reinterpret_cast<unsigned*>(&out[(size_t)(n0 + n)*R + k0 + kp*2]) = lo | (hi << 16);
    }
}

// ---------------- fp32 -> bf16 flat convert ----------------
__global__ __launch_bounds__(256) void k_cvt(const float* __restrict__ in,
                                             bf16* __restrict__ out) {
    int i = blockIdx.x*256 + threadIdx.x;
    f32x4 v = ((const f32x4*)in)[i];
    s16x4 o;
    #pragma unroll
    for (int j = 0; j < 4; j++) o[j] = f2bf_s(v[j]);
    ((s16x4*)out)[i] = o;
}

// ---------------- gate softmax + act-weight softmax (all f32) ----------------
__global__ __launch_bounds__(256) void k_gate(const float* __restrict__ x,
                                              const float* __restrict__ gw,
                                              const float* __restrict__ gb,
                                              const float* __restrict__ aw_in,
                                              float* __restrict__ gate,
                                              float* __restrict__ actw) {
    int b = blockIdx.x, t = threadIdx.x, w = t >> 6, lane = t & 63;
    __shared__ float l[4];
    float s = 0.f;
    for (int k = lane; k < 1024; k += 64)
        s += x[(size_t)b*1024 + k] * gw[k*4 + w];
    #pragma unroll
    for (int off = 32; off; off >>= 1) s += __shfl_xor(s, off);
    if (lane == 0) l[w] = s + gb[w];
    __syncthreads();
    if (t == 0) {
        float m = fmaxf(fmaxf(l[0], l[1]), fmaxf(l[2], l[3]));
        float e0 = __expf(l[0]-m), e1 = __expf(l[1]-m), e2 = __expf(l[2]-m), e3 = __expf(l[3]-m);
        float inv = 1.f / (e0+e1+e2+e3);
        gate[b*4+0] = e0*inv; gate[b*4+1] = e1*inv;
        gate[b*4+2] = e2*inv; gate[b*4+3] = e3*inv;
    }
    if (b == 0 && t == 64) {
        float a[9]; float m = -1e30f;
        for (int i = 0; i < 9; i++) { a[i] = aw_in[i]; m = fmaxf(m, a[i]); }
        float ss = 0.f;
        for (int i = 0; i < 9; i++) { a[i] = __expf(a[i]-m); ss += a[i]; }
        float inv = 1.f / ss;
        for (int i = 0; i < 9; i++) actw[i] = a[i]*inv;
    }
}

// ---------------- GEMM (BT): C(MxN) = A(MxK) @ Bt(NxK)^T, 128x128 tile, BK=32 ----------------
// global_load_lds width-16 staging. MODE 3: outF=acc [read]; MODE 4: hidden epilogue
// (gate contraction -> LDS redistribute -> dense qact); MODE 5: fused 3-head epilogue.
template <int MODE>
__global__ __launch_bounds__(256, 2) void gemm_bt(
        const bf16* __restrict__ A, const bf16* __restrict__ Bt,
        int K,
        const float* __restrict__ bias, const float* __restrict__ bias2,
        const float* __restrict__ bias3,
        float* __restrict__ outF, bf16* __restrict__ outH, bf16* __restrict__ outH2,
        const float* __restrict__ gate, const float* __restrict__ actw,
        const float* __restrict__ mask, int outStride) {
    __shared__ __align__(16) union SMem {
        struct { short a[128*32]; short b[128*32]; } tl;
        float z[4096];
    } sm;
    int t = threadIdx.x, lane = t & 63;
    int rowBase = blockIdx.y * 128, colBase = blockIdx.x * 128;
    int lm = lane & 15, lq = lane >> 4;
    int w = t >> 6;
    int qm = (w >> 1) * 64, qn = (w & 1) * 64;

    f32x4 acc[4][4];
    #pragma unroll
    for (int i = 0; i < 4; i++)
        #pragma unroll
        for (int j = 0; j < 4; j++) acc[i][j] = (f32x4){0.f, 0.f, 0.f, 0.f};

    // async staging map: chunk c = w*128 + lane (+64); row = c>>2, kofs = (c&3)*8
    int c0 = w*128 + lane, c1 = c0 + 64;
    int r0 = c0 >> 2, ko0 = (c0 & 3) * 8;
    int r1 = c1 >> 2, ko1 = (c1 & 3) * 8;
    short* dstA0 = sm.tl.a + w*1024;
    short* dstA1 = sm.tl.a + w*1024 + 512;
    short* dstB0 = sm.tl.b + w*1024;
    short* dstB1 = sm.tl.b + w*1024 + 512;

    for (int k0 = 0; k0 < K; k0 += 32) {
        __syncthreads();
        async_load16(A  + (size_t)(rowBase + r0)*K + k0 + ko0, dstA0);
        async_load16(A  + (size_t)(rowBase + r1)*K + k0 + ko1, dstA1);
        async_load16(Bt + (size_t)(colBase + r0)*K + k0 + ko0, dstB0);
        async_load16(Bt + (size_t)(colBase + r1)*K + k0 + ko1, dstB1);
        __syncthreads();
        s16x8 af[4], bfr[4];
        #pragma unroll
        for (int mi = 0; mi < 4; mi++)
            af[mi] = *reinterpret_cast<const s16x8*>(sm.tl.a + (qm + mi*16 + lm)*32 + lq*8);
        #pragma unroll
        for (int ni = 0; ni < 4; ni++)
            bfr[ni] = *reinterpret_cast<const s16x8*>(sm.tl.b + (qn + ni*16 + lm)*32 + lq*8);
        #pragma unroll
        for (int mi = 0; mi < 4; mi++)
            #pragma unroll
            for (int ni = 0; ni < 4; ni++)
                acc[mi][ni] = __builtin_amdgcn_mfma_f32_16x16x32_bf16(af[mi], bfr[ni], acc[mi][ni], 0, 0, 0);
    }

    if (MODE == 4) {
        // gate-contract over n within lanes, park z in LDS, then dense qact pass.
        __syncthreads();   // all LDS tile reads done; safe to overlay sm.z
        #pragma unroll
        for (int mi = 0; mi < 4; mi++) {
            int rowl0 = qm + mi*16 + lq*4;
            #pragma unroll
            for (int ni = 0; ni < 4; ni++) {
                int col = colBase + qn + ni*16 + lm;
                int n = col & 3;
                float bb = bias[col];
                f32x4 v = acc[mi][ni];
                #pragma unroll
                for (int r = 0; r < 4; r++) v[r] = (v[r] + bb) * gate[(rowBase + rowl0 + r)*4 + n];
                #pragma unroll
                for (int r = 0; r < 4; r++) v[r] += __shfl_xor(v[r], 1);
                #pragma unroll
                for (int r = 0; r < 4; r++) v[r] += __shfl_xor(v[r], 2);
                if ((lane & 3) == 0) {
                    int ul = ((w & 1) << 4) + ni*4 + (lm >> 2);   // 0..31
                    #pragma unroll
                    for (int r = 0; r < 4; r++)
                        sm.z[(rowl0 + r)*32 + ul] = v[r];
                }
            }
        }
        __syncthreads();
        float aw[9];
        #pragma unroll
        for (int i = 0; i < 9; i++) aw[i] = actw[i];
        int u0 = colBase >> 2;
        #pragma unroll
        for (int i = 0; i < 16; i++) {
            int idx = t + i*256;
            int row = idx >> 5, ul = idx & 31;
            int ug = u0 + ul;
            float zz = sm.z[idx];
            outH[(size_t)(rowBase + row)*outStride + ug] = __float2bfloat16(qact(zz, aw) * mask[ug]);
        }
    } else if (MODE == 5) {
        #pragma unroll
        for (int mi = 0; mi < 4; mi++) {
            int row0 = rowBase + qm + mi*16 + lq*4;
            #pragma unroll
            for (int ni = 0; ni < 4; ni++) {
                int col = colBase + qn + ni*16 + lm;
                if (col < 2048) {
                    float bb = bias[col];
                    #pragma unroll
                    for (int r = 0; r < 4; r++)
                        outH[(size_t)(row0 + r)*2048 + col] = __float2bfloat16(acc[mi][ni][r] + bb);
                } else if (col < 3072) {
                    int c = col - 2048;
                    float bb = bias2[c];
                    #pragma unroll
                    for (int r = 0; r < 4; r++)
                        outH2[(size_t)(row0 + r)*1024 + c] = __float2bfloat16(fast_tanh(acc[mi][ni][r] + bb));
                } else {
                    int c = col - 3072;
                    float bb = bias3[c];
                    #pragma unroll
                    for (int r = 0; r < 4; r++)
                        outF[(size_t)(row0 + r)*512 + c] = acc[mi][ni][r] + bb;
                }
            }
        }
    } else {  // MODE 3
        #pragma unroll
        for (int mi = 0; mi < 4; mi++) {
            int row0 = rowBase + qm + mi*16 + lq*4;
            #pragma unroll
            for (int ni = 0; ni < 4; ni++) {
                int col = colBase + qn + ni*16 + lm;
                #pragma unroll
                for (int r = 0; r < 4; r++)
                    outF[(size_t)(row0 + r)*outStride + col] = acc[mi][ni][r];
            }
        }
    }
}

// ---------------- in-place row softmax over 2048 cols (bf16 buffer) ----------------
__global__ __launch_bounds__(256) void k_softmax(bf16* __restrict__ ratt) {
    int b = blockIdx.x, t = threadIdx.x, w = t >> 6, lane = t & 63;
    __shared__ float red[8];
    bf16* row = ratt + (size_t)b*2048;
    float v[8];
    float mx = -1e30f;
    #pragma unroll
    for (int j = 0; j < 8; j++) {
        v[j] = __bfloat162float(row[t + j*256]);
        mx = fmaxf(mx, v[j]);
    }
    #pragma unroll
    for (int off = 32; off; off >>= 1) mx = fmaxf(mx, __shfl_xor(mx, off));
    if (lane == 0) red[w] = mx;
    __syncthreads();
    mx = fmaxf(fmaxf(red[0], red[1]), fmaxf(red[2], red[3]));
    float s = 0.f;
    #pragma unroll
    for (int j = 0; j < 8; j++) { v[j] = __expf(v[j] - mx); s += v[j]; }
    #pragma unroll
    for (int off = 32; off; off >>= 1) s += __shfl_xor(s, off);
    if (lane == 0) red[4 + w] = s;
    __syncthreads();
    float inv = 1.f / (red[4] + red[5] + red[6] + red[7]);
    #pragma unroll
    for (int j = 0; j < 8; j++)
        row[t + j*256] = __float2bfloat16(v[j] * inv);
}

// ---------------- column-mean partials ----------------
__global__ __launch_bounds__(256) void k_colpart(const bf16* __restrict__ ratt,
                                                 const bf16* __restrict__ cand,
                                                 float* __restrict__ part) {
    int ct = blockIdx.x, rc = blockIdx.y, t = threadIdx.x;
    int col = ct*256 + t;
    const bf16* src; int stride, c;
    if (ct < 8) { src = ratt; stride = 2048; c = col; }
    else        { src = cand; stride = 1024; c = col - 2048; }
    float s = 0.f;
    int r0 = rc*128;
    for (int r = 0; r < 128; r++)
        s += __bfloat162float(src[(size_t)(r0 + r)*stride + c]);
    part[rc*3072 + col] = s;
}

__global__ __launch_bounds__(256) void k_colfin(const float* __restrict__ part,
                                                const float* __restrict__ update_gate,
                                                float* __restrict__ u,
                                                float* __restrict__ cmean) {
    int col = blockIdx.x*256 + threadIdx.x;
    float s = 0.f;
    #pragma unroll
    for (int rc = 0; rc < 8; rc++) s += part[rc*3072 + col];
    s *= (1.f/1024.f);
    if (col < 2048) u[col] = s * update_gate[col];
    else            cmean[col - 2048] = s;
}

// ---------------- new_mem blend (f32 out) ----------------
__global__ __launch_bounds__(256) void k_newmem(const float* __restrict__ mem,
                                                const float* __restrict__ u,
                                                const float* __restrict__ cmean,
                                                float* __restrict__ out1) {
    int idx = blockIdx.x*256 + threadIdx.x;
    int m = idx >> 10, d = idx & 1023;
    float um = u[m];
    out1[idx] = mem[idx] * (1.f - um) + um * cmean[d];
}

// ---------------- critic + final gating: 1 batch row per block, LDS-staged ----------------
__global__ __launch_bounds__(256) void k_critic(
        const float* __restrict__ readv, const float* __restrict__ preds,
        const bf16* __restrict__ hidden,
        const float* cw1, const float* cb1, const float* cw2, const float* cb2,
        const float* cw3, const float* cb3, const float* cw4, const float* cb4,
        const float* cw5, const float* cb5, const float* thr,
        float* __restrict__ out0) {
    __shared__ __align__(16) float sx[1024];
    __shared__ __align__(16) float sp[512];
    __shared__ __align__(16) short sh[2048];
    __shared__ float part[8][32];
    __shared__ float feat[96];
    __shared__ float fused[64];
    __shared__ float gsh;
    int b = blockIdx.x, t = threadIdx.x;
    int j = t & 31, g = t >> 5;

    ((f32x4*)sx)[t] = ((const f32x4*)(readv + (size_t)b*1024))[t];
    if (t < 128) ((f32x4*)sp)[t] = ((const f32x4*)(preds + (size_t)b*512))[t];
    ((s16x8*)sh)[t] = ((const s16x8*)(hidden + (size_t)b*2048))[t];
    __syncthreads();

    {
        float a = 0.f;
        int k0 = g*128;
        #pragma unroll 4
        for (int k = k0; k < k0 + 128; k++) a += sx[k] * cw1[k*32 + j];
        part[g][j] = a;
    }
    __syncthreads();
    if (t < 32) {
        float s = 0.f;
        #pragma unroll
        for (int i = 0; i < 8; i++) s += part[i][t];
        feat[t] = fmaxf(s + cb1[t], 0.f);
    }
    __syncthreads();
    {
        float a = 0.f;
        int k0 = g*64;
        #pragma unroll 4
        for (int k = k0; k < k0 + 64; k++) a += sp[k] * cw2[k*32 + j];
        part[g][j] = a;
    }
    __syncthreads();
    if (t < 32) {
        float s = 0.f;
        #pragma unroll
        for (int i = 0; i < 8; i++) s += part[i][t];
        feat[32 + t] = fmaxf(s + cb2[t], 0.f);
    }
    __syncthreads();
    {
        float a = 0.f;
        int k0 = g*256;
        #pragma unroll 4
        for (int k = k0; k < k0 + 256; k++) {
            bf16 hv = *reinterpret_cast<const bf16*>(&sh[k]);
            a += __bfloat162float(hv) * cw3[k*32 + j];
        }
        part[g][j] = a;
    }
    __syncthreads();
    if (t < 32) {
        float s = 0.f;
        #pragma unroll
        for (int i = 0; i < 8; i++) s += part[i][t];
        feat[64 + t] = fmaxf(s + cb3[t], 0.f);
    }
    __syncthreads();
    if (t < 64) {
        float s = 0.f;
        #pragma unroll 8
        for (int k = 0; k < 96; k++) s += feat[k] * cw4[k*64 + t];
        fused[t] = fmaxf(s + cb4[t], 0.f);
    }
    __syncthreads();
    if (t < 64) {
        float v = fused[t] * cw5[t*2];
        #pragma unroll
        for (int off = 32; off; off >>= 1) v += __shfl_xor(v, off);
        if (t == 0)
            gsh = 1.f / (1.f + __expf(-(v + cb5[0] - thr[0])));
    }
    __syncthreads();
    float gg = gsh;
    #pragma unroll
    for (int o = t; o < 512; o += 256)
        out0[(size_t)b*512 + o] = sp[o] * gg;
}

extern "C" void kernel_launch(void* const* d_in, const int* in_sizes, int n_in,
                              void* d_out, int out_size, void* d_ws, size_t ws_size,
                              hipStream_t stream) {
    const float* x        = (const float*)d_in[0];
    const float* w_       = (const float*)d_in[1];   // (1024, 8192)
    const float* b_bias   = (const float*)d_in[2];
    const float* gate_w   = (const float*)d_in[3];
    const float* gate_b   = (const float*)d_in[4];
    const float* act_w    = (const float*)d_in[5];
    const float* mask     = (const float*)d_in[6];
    const float* mem      = (const float*)d_in[7];   // (2048, 1024)
    const float* att_w    = (const float*)d_in[8];   // (2048, 2048)
    const float* att_b    = (const float*)d_in[9];
    const float* write_w  = (const float*)d_in[10];  // (2048, 1024)
    const float* write_b  = (const float*)d_in[11];
    const float* upd_gate = (const float*)d_in[12];
    const float* out_w    = (const float*)d_in[13];  // (2048, 512)
    const float* out_b    = (const float*)d_in[14];
    const float* cw1 = (const float*)d_in[15]; const float* cb1 = (const float*)d_in[16];
    const float* cw2 = (const float*)d_in[17]; const float* cb2 = (const float*)d_in[18];
    const float* cw3 = (const float*)d_in[19]; const float* cb3 = (const float*)d_in[20];
    const float* cw4 = (const float*)d_in[21]; const float* cb4 = (const float*)d_in[22];
    const float* cw5 = (const float*)d_in[23]; const float* cb5 = (const float*)d_in[24];
    const float* thr = (const float*)d_in[25];

    char* ws = (char*)d_ws;
    float* gate   = (float*)(ws + GATE_OFF);
    float* actw   = (float*)(ws + ACTW_OFF);
    float* uvec   = (float*)(ws + U_OFF);
    float* cmean  = (float*)(ws + CMEAN_OFF);
    float* part   = (float*)(ws + PART_OFF);
    bf16*  hidden = (bf16*)(ws + HIDDEN_OFF);
    bf16*  ratt   = (bf16*)(ws + RATT_OFF);
    bf16*  cand   = (bf16*)(ws + CAND_OFF);
    float* preds  = (float*)(ws + PREDS_OFF);
    float* readv  = (float*)(ws + READ_OFF);
    bf16*  xbf    = (bf16*)(ws + XBF_OFF);
    bf16*  wT     = (bf16*)(ws + WT_OFF);
    bf16*  catT   = (bf16*)(ws + CATT_OFF);
    bf16*  memT   = (bf16*)(ws + MEMT_OFF);

    float* out0 = (float*)d_out;            // (1024, 512)
    float* out1 = out0 + 1024*512;          // (2048, 1024)

    dim3 tb(64, 4);
    // prepass: convert + transpose weights to bf16 N x K
    k_cvt<<<1024, 256, 0, stream>>>(x, xbf);
    k_transpose<<<dim3(128, 16), tb, 0, stream>>>(w_,      wT,             1024, 8192);
    k_transpose<<<dim3(32, 32),  tb, 0, stream>>>(att_w,   catT,           2048, 2048);
    k_transpose<<<dim3(16, 32),  tb, 0, stream>>>(write_w, catT + 2048ull*2048, 2048, 1024);
    k_transpose<<<dim3(8, 32),   tb, 0, stream>>>(out_w,   catT + 3072ull*2048, 2048, 512);
    k_transpose<<<dim3(16, 32),  tb, 0, stream>>>(mem,     memT,           2048, 1024);

    k_gate<<<1024, 256, 0, stream>>>(x, gate_w, gate_b, act_w, gate, actw);

    // G1: hidden = qact((x@w + b)·gate) * mask     [M=1024, N=8192, K=1024]
    gemm_bt<4><<<dim3(64, 8), 256, 0, stream>>>(xbf, wT, 1024,
        b_bias, nullptr, nullptr, nullptr, hidden, nullptr, gate, actw, mask, 2048);
    // G234 fused: [att|write|out] heads            [M=1024, N=3584, K=2048]
    gemm_bt<5><<<dim3(28, 8), 256, 0, stream>>>(hidden, catT, 2048,
        att_b, write_b, out_b, preds, ratt, cand, nullptr, nullptr, nullptr, 0);
    k_softmax<<<1024, 256, 0, stream>>>(ratt);
    // G5: read = ratt @ mem (f32)                  [M=1024, N=1024, K=2048]
    gemm_bt<3><<<dim3(8, 8), 256, 0, stream>>>(ratt, memT, 2048,
        nullptr, nullptr, nullptr, readv, nullptr, nullptr, nullptr, nullptr, nullptr, 1024);

    k_colpart<<<dim3(12, 8), 256, 0, stream>>>(ratt, cand, part);
    k_colfin<<<12, 256, 0, stream>>>(part, upd_gate, uvec, cmean);
    k_newmem<<<8192, 256, 0, stream>>>(mem, uvec, cmean, out1);
    k_critic<<<1024, 256, 0, stream>>>(readv, preds, hidden,
        cw1, cb1, cw2, cb2, cw3, cb3, cw4, cb4, cw5, cb5, thr, out0);
}

// Round 10
// 332.487 us; speedup vs baseline: 1.9626x; 1.0941x over previous
//
#include <hip/hip_runtime.h>
#include <hip/hip_bf16.h>
#include <math.h>

typedef __attribute__((ext_vector_type(4))) float f32x4;
typedef __attribute__((ext_vector_type(8))) short s16x8;
typedef __attribute__((ext_vector_type(4))) short s16x4;
typedef __hip_bfloat16 bf16;

#define MB (1024ull*1024ull)
// workspace layout (bytes) — total 53 MB
#define GATE_OFF    (0ull)          // 1024*4 f32
#define ACTW_OFF    (16ull*1024)    // 9 f32
#define U_OFF       (20ull*1024)    // 2048 f32
#define CMEAN_OFF   (28ull*1024)    // 1024 f32
#define PART_OFF    (64ull*1024)    // 8*3072 f32
#define HIDDEN_OFF  (1ull*MB)       // bf16 1024x2048 (4MB)
#define RATT_OFF    (5ull*MB)       // bf16 1024x2048 (4MB)
#define CAND_OFF    (9ull*MB)       // bf16 1024x1024 (2MB)
#define PREDS_OFF   (11ull*MB)      // f32 1024x512  (2MB)
#define READ_OFF    (13ull*MB)      // f32 1024x1024 (4MB)
#define XBF_OFF     (17ull*MB)      // bf16 1024x1024 (2MB)
#define WT_OFF      (19ull*MB)      // bf16 8192x1024 (16MB) -> ends 35
#define CATT_OFF    (35ull*MB)      // bf16 3584x2048 (14MB) -> ends 49  [att|write|out]^T
#define MEMT_OFF    (49ull*MB)      // bf16 1024x2048 (4MB) -> ends 53

__device__ __forceinline__ short f2bf_s(float f) {
    bf16 h = __float2bfloat16(f);
    return *reinterpret_cast<short*>(&h);
}

__device__ __forceinline__ void async_load16(const bf16* g, short* l) {
    __builtin_amdgcn_global_load_lds((const __attribute__((address_space(1))) void*)g,
                                     (__attribute__((address_space(3))) void*)l, 16, 0, 0);
}

// fast tanh: 1 - 2/(e^{2x}+1); inf-safe at both ends
__device__ __forceinline__ float fast_tanh(float x) {
    float e2x = __expf(2.f * x);
    return 1.f - 2.f / (e2x + 1.f);
}

// fast 9-way activation mix — __expf algebra only (validated round 9, absmax unchanged)
__device__ __forceinline__ float qact(float x, const float* w) {
    float ex  = __expf(x);
    float r1  = 1.f / (1.f + ex);
    float sig = 1.f - r1;
    float em1 = ex - 1.f;
    float elu = x > 0.f ? x : em1;
    float e2x = ex * ex;
    float th  = 1.f - 2.f / (e2x + 1.f);
    float rel = fmaxf(x, 0.f);
    float silu = x * sig;
    float u   = 0.7978845608028654f * (x + 0.044715f * x * x * x);
    float e2u = __expf(2.f * u);
    float gel = x * (1.f - 1.f / (e2u + 1.f));
    float sel = 1.0507009873554805f * (x > 0.f ? x : 1.6732632423543772f * em1);
    float t   = 1.f + ex;
    float t2  = t * t;
    float mish = x * (1.f - 2.f / (t2 + 1.f));
    return w[0]*sig + w[1]*elu + w[2]*th + w[3]*rel + w[4]*silu
         + w[5]*gel + w[6]*sel + w[7]*mish + w[8]*x;
}

// ---------------- fp32 (R x C) -> bf16 (C x R) transpose, 64x64 tiles ----------------
__global__ __launch_bounds__(256) void k_transpose(const float* __restrict__ in,
                                                   bf16* __restrict__ out, int R, int C) {
    __shared__ short tile[64][66];
    int k0 = blockIdx.y*64, n0 = blockIdx.x*64;
    int tx = threadIdx.x, ty = threadIdx.y;     // (64,4)
    #pragma unroll
    for (int j = 0; j < 16; j++) {
        int k = ty + j*4;
        tile[tx][k] = f2bf_s(in[(size_t)(k0 + k)*C + n0 + tx]);
    }
    __syncthreads();
    int t = ty*64 + tx;
    int kp = t & 31, nrow = t >> 5;
    #pragma unroll
    for (int jj = 0; jj < 8; jj++) {
        int n = nrow + jj*8;
        unsigned lo = (unsigned short)tile[n][kp*2];
        unsigned hi = (unsigned short)tile[n][kp*2 + 1];
        *reinterpret_cast<unsigned*>(&out[(size_t)(n0 + n)*R + k0 + kp*2]) = lo | (hi << 16);
    }
}

// ---------------- fp32 -> bf16 flat convert ----------------
__global__ __launch_bounds__(256) void k_cvt(const float* __restrict__ in,
                                             bf16* __restrict__ out) {
    int i = blockIdx.x*256 + threadIdx.x;
    f32x4 v = ((const f32x4*)in)[i];
    s16x4 o;
    #pragma unroll
    for (int j = 0; j < 4; j++) o[j] = f2bf_s(v[j]);
    ((s16x4*)out)[i] = o;
}

// ---------------- gate softmax + act-weight softmax (all f32) ----------------
__global__ __launch_bounds__(256) void k_gate(const float* __restrict__ x,
                                              const float* __restrict__ gw,
                                              const float* __restrict__ gb,
                                              const float* __restrict__ aw_in,
                                              float* __restrict__ gate,
                                              float* __restrict__ actw) {
    int b = blockIdx.x, t = threadIdx.x, w = t >> 6, lane = t & 63;
    __shared__ float l[4];
    float s = 0.f;
    for (int k = lane; k < 1024; k += 64)
        s += x[(size_t)b*1024 + k] * gw[k*4 + w];
    #pragma unroll
    for (int off = 32; off; off >>= 1) s += __shfl_xor(s, off);
    if (lane == 0) l[w] = s + gb[w];
    __syncthreads();
    if (t == 0) {
        float m = fmaxf(fmaxf(l[0], l[1]), fmaxf(l[2], l[3]));
        float e0 = __expf(l[0]-m), e1 = __expf(l[1]-m), e2 = __expf(l[2]-m), e3 = __expf(l[3]-m);
        float inv = 1.f / (e0+e1+e2+e3);
        gate[b*4+0] = e0*inv; gate[b*4+1] = e1*inv;
        gate[b*4+2] = e2*inv; gate[b*4+3] = e3*inv;
    }
    if (b == 0 && t == 64) {
        float a[9]; float m = -1e30f;
        for (int i = 0; i < 9; i++) { a[i] = aw_in[i]; m = fmaxf(m, a[i]); }
        float ss = 0.f;
        for (int i = 0; i < 9; i++) { a[i] = __expf(a[i]-m); ss += a[i]; }
        float inv = 1.f / ss;
        for (int i = 0; i < 9; i++) actw[i] = a[i]*inv;
    }
}

// ---------------- GEMM (BT): C(MxN) = A(MxK) @ Bt(NxK)^T, 128x128 tile, BK=32 ----------------
template <int MODE>
__global__ __launch_bounds__(256, 2) void gemm_bt(
        const bf16* __restrict__ A, const bf16* __restrict__ Bt,
        int K,
        const float* __restrict__ bias, const float* __restrict__ bias2,
        const float* __restrict__ bias3,
        float* __restrict__ outF, bf16* __restrict__ outH, bf16* __restrict__ outH2,
        const float* __restrict__ gate, const float* __restrict__ actw,
        const float* __restrict__ mask, int outStride) {
    __shared__ __align__(16) union SMem {
        struct { short a[128*32]; short b[128*32]; } tl;
        float z[4096];
    } sm;
    int t = threadIdx.x, lane = t & 63;
    int rowBase = blockIdx.y * 128, colBase = blockIdx.x * 128;
    int lm = lane & 15, lq = lane >> 4;
    int w = t >> 6;
    int qm = (w >> 1) * 64, qn = (w & 1) * 64;

    f32x4 acc[4][4];
    #pragma unroll
    for (int i = 0; i < 4; i++)
        #pragma unroll
        for (int j = 0; j < 4; j++) acc[i][j] = (f32x4){0.f, 0.f, 0.f, 0.f};

    int c0 = w*128 + lane, c1 = c0 + 64;
    int r0 = c0 >> 2, ko0 = (c0 & 3) * 8;
    int r1 = c1 >> 2, ko1 = (c1 & 3) * 8;
    short* dstA0 = sm.tl.a + w*1024;
    short* dstA1 = sm.tl.a + w*1024 + 512;
    short* dstB0 = sm.tl.b + w*1024;
    short* dstB1 = sm.tl.b + w*1024 + 512;

    for (int k0 = 0; k0 < K; k0 += 32) {
        __syncthreads();
        async_load16(A  + (size_t)(rowBase + r0)*K + k0 + ko0, dstA0);
        async_load16(A  + (size_t)(rowBase + r1)*K + k0 + ko1, dstA1);
        async_load16(Bt + (size_t)(colBase + r0)*K + k0 + ko0, dstB0);
        async_load16(Bt + (size_t)(colBase + r1)*K + k0 + ko1, dstB1);
        __syncthreads();
        s16x8 af[4], bfr[4];
        #pragma unroll
        for (int mi = 0; mi < 4; mi++)
            af[mi] = *reinterpret_cast<const s16x8*>(sm.tl.a + (qm + mi*16 + lm)*32 + lq*8);
        #pragma unroll
        for (int ni = 0; ni < 4; ni++)
            bfr[ni] = *reinterpret_cast<const s16x8*>(sm.tl.b + (qn + ni*16 + lm)*32 + lq*8);
        #pragma unroll
        for (int mi = 0; mi < 4; mi++)
            #pragma unroll
            for (int ni = 0; ni < 4; ni++)
                acc[mi][ni] = __builtin_amdgcn_mfma_f32_16x16x32_bf16(af[mi], bfr[ni], acc[mi][ni], 0, 0, 0);
    }

    if (MODE == 4) {
        __syncthreads();
        #pragma unroll
        for (int mi = 0; mi < 4; mi++) {
            int rowl0 = qm + mi*16 + lq*4;
            #pragma unroll
            for (int ni = 0; ni < 4; ni++) {
                int col = colBase + qn + ni*16 + lm;
                int n = col & 3;
                float bb = bias[col];
                f32x4 v = acc[mi][ni];
                #pragma unroll
                for (int r = 0; r < 4; r++) v[r] = (v[r] + bb) * gate[(rowBase + rowl0 + r)*4 + n];
                #pragma unroll
                for (int r = 0; r < 4; r++) v[r] += __shfl_xor(v[r], 1);
                #pragma unroll
                for (int r = 0; r < 4; r++) v[r] += __shfl_xor(v[r], 2);
                if ((lane & 3) == 0) {
                    int ul = ((w & 1) << 4) + ni*4 + (lm >> 2);
                    #pragma unroll
                    for (int r = 0; r < 4; r++)
                        sm.z[(rowl0 + r)*32 + ul] = v[r];
                }
            }
        }
        __syncthreads();
        float aw[9];
        #pragma unroll
        for (int i = 0; i < 9; i++) aw[i] = actw[i];
        int u0 = colBase >> 2;
        #pragma unroll
        for (int i = 0; i < 16; i++) {
            int idx = t + i*256;
            int row = idx >> 5, ul = idx & 31;
            int ug = u0 + ul;
            float zz = sm.z[idx];
            outH[(size_t)(rowBase + row)*outStride + ug] = __float2bfloat16(qact(zz, aw) * mask[ug]);
        }
    } else if (MODE == 5) {
        #pragma unroll
        for (int mi = 0; mi < 4; mi++) {
            int row0 = rowBase + qm + mi*16 + lq*4;
            #pragma unroll
            for (int ni = 0; ni < 4; ni++) {
                int col = colBase + qn + ni*16 + lm;
                if (col < 2048) {
                    float bb = bias[col];
                    #pragma unroll
                    for (int r = 0; r < 4; r++)
                        outH[(size_t)(row0 + r)*2048 + col] = __float2bfloat16(acc[mi][ni][r] + bb);
                } else if (col < 3072) {
                    int c = col - 2048;
                    float bb = bias2[c];
                    #pragma unroll
                    for (int r = 0; r < 4; r++)
                        outH2[(size_t)(row0 + r)*1024 + c] = __float2bfloat16(fast_tanh(acc[mi][ni][r] + bb));
                } else {
                    int c = col - 3072;
                    float bb = bias3[c];
                    #pragma unroll
                    for (int r = 0; r < 4; r++)
                        outF[(size_t)(row0 + r)*512 + c] = acc[mi][ni][r] + bb;
                }
            }
        }
    } else {  // MODE 3
        #pragma unroll
        for (int mi = 0; mi < 4; mi++) {
            int row0 = rowBase + qm + mi*16 + lq*4;
            #pragma unroll
            for (int ni = 0; ni < 4; ni++) {
                int col = colBase + qn + ni*16 + lm;
                #pragma unroll
                for (int r = 0; r < 4; r++)
                    outF[(size_t)(row0 + r)*outStride + col] = acc[mi][ni][r];
            }
        }
    }
}

// ---------------- in-place row softmax over 2048 cols (bf16 buffer) ----------------
__global__ __launch_bounds__(256) void k_softmax(bf16* __restrict__ ratt) {
    int b = blockIdx.x, t = threadIdx.x, w = t >> 6, lane = t & 63;
    __shared__ float red[8];
    bf16* row = ratt + (size_t)b*2048;
    float v[8];
    float mx = -1e30f;
    #pragma unroll
    for (int j = 0; j < 8; j++) {
        v[j] = __bfloat162float(row[t + j*256]);
        mx = fmaxf(mx, v[j]);
    }
    #pragma unroll
    for (int off = 32; off; off >>= 1) mx = fmaxf(mx, __shfl_xor(mx, off));
    if (lane == 0) red[w] = mx;
    __syncthreads();
    mx = fmaxf(fmaxf(red[0], red[1]), fmaxf(red[2], red[3]));
    float s = 0.f;
    #pragma unroll
    for (int j = 0; j < 8; j++) { v[j] = __expf(v[j] - mx); s += v[j]; }
    #pragma unroll
    for (int off = 32; off; off >>= 1) s += __shfl_xor(s, off);
    if (lane == 0) red[4 + w] = s;
    __syncthreads();
    float inv = 1.f / (red[4] + red[5] + red[6] + red[7]);
    #pragma unroll
    for (int j = 0; j < 8; j++)
        row[t + j*256] = __float2bfloat16(v[j] * inv);
}

// ---------------- column-mean partials ----------------
__global__ __launch_bounds__(256) void k_colpart(const bf16* __restrict__ ratt,
                                                 const bf16* __restrict__ cand,
                                                 float* __restrict__ part) {
    int ct = blockIdx.x, rc = blockIdx.y, t = threadIdx.x;
    int col = ct*256 + t;
    const bf16* src; int stride, c;
    if (ct < 8) { src = ratt; stride = 2048; c = col; }
    else        { src = cand; stride = 1024; c = col - 2048; }
    float s = 0.f;
    int r0 = rc*128;
    for (int r = 0; r < 128; r++)
        s += __bfloat162float(src[(size_t)(r0 + r)*stride + c]);
    part[rc*3072 + col] = s;
}

__global__ __launch_bounds__(256) void k_colfin(const float* __restrict__ part,
                                                const float* __restrict__ update_gate,
                                                float* __restrict__ u,
                                                float* __restrict__ cmean) {
    int col = blockIdx.x*256 + threadIdx.x;
    float s = 0.f;
    #pragma unroll
    for (int rc = 0; rc < 8; rc++) s += part[rc*3072 + col];
    s *= (1.f/1024.f);
    if (col < 2048) u[col] = s * update_gate[col];
    else            cmean[col - 2048] = s;
}

// ---------------- new_mem blend (f32 out) ----------------
__global__ __launch_bounds__(256) void k_newmem(const float* __restrict__ mem,
                                                const float* __restrict__ u,
                                                const float* __restrict__ cmean,
                                                float* __restrict__ out1) {
    int idx = blockIdx.x*256 + threadIdx.x;
    int m = idx >> 10, d = idx & 1023;
    float um = u[m];
    out1[idx] = mem[idx] * (1.f - um) + um * cmean[d];
}

// ---------------- critic: 2 rows/block, f32x4 weight loads ----------------
// L2-traffic fix: weight vectors loaded once per 2 rows (229 MB vs 458 MB), 16B/lane.
// Thread map: j4 = t&7 (feature quad, f32x4), kg = t>>3 (32 k-groups).
__global__ __launch_bounds__(256) void k_critic(
        const float* __restrict__ readv, const float* __restrict__ preds,
        const bf16* __restrict__ hidden,
        const float* cw1, const float* cb1, const float* cw2, const float* cb2,
        const float* cw3, const float* cb3, const float* cw4, const float* cb4,
        const float* cw5, const float* cb5, const float* thr,
        float* __restrict__ out0) {
    __shared__ __align__(16) float sx[2*1024];
    __shared__ __align__(16) float sp[2*512];
    __shared__ __align__(16) short sh[2*2048];
    __shared__ __align__(16) f32x4 part[2][32][8];   // 8KB
    __shared__ float feat[2][96];
    __shared__ float fused[2][64];
    __shared__ float gsh[2];
    int b0 = blockIdx.x * 2, t = threadIdx.x;
    int j4 = t & 7, kg = t >> 3;

    // stage 2 rows of each activation (16B vector loads)
    ((f32x4*)sx)[t]       = ((const f32x4*)(readv + (size_t)b0*1024))[t];
    ((f32x4*)sx)[t + 256] = ((const f32x4*)(readv + (size_t)b0*1024))[t + 256];
    ((f32x4*)sp)[t]       = ((const f32x4*)(preds + (size_t)b0*512))[t];
    ((s16x8*)sh)[t]       = ((const s16x8*)(hidden + (size_t)b0*2048))[t];
    ((s16x8*)sh)[t + 256] = ((const s16x8*)(hidden + (size_t)b0*2048))[t + 256];
    __syncthreads();

    // ---- f1: readv(1024) @ cw1(1024x32) ----
    {
        const f32x4* wv = (const f32x4*)cw1;   // row k = 8 x f32x4
        f32x4 a0 = (f32x4){0,0,0,0}, a1 = (f32x4){0,0,0,0};
        int k0 = kg*32;
        #pragma unroll 4
        for (int k = k0; k < k0 + 32; k++) {
            f32x4 wq = wv[k*8 + j4];
            a0 += sx[k] * wq;
            a1 += sx[1024 + k] * wq;
        }
        part[0][kg][j4] = a0; part[1][kg][j4] = a1;
    }
    __syncthreads();
    if (t < 64) {
        int r = t >> 5, f = t & 31;
        float s = 0.f;
        #pragma unroll
        for (int i = 0; i < 32; i++) s += part[r][i][f >> 2][f & 3];
        feat[r][f] = fmaxf(s + cb1[f], 0.f);
    }
    __syncthreads();
    // ---- f2: preds(512) @ cw2(512x32) ----
    {
        const f32x4* wv = (const f32x4*)cw2;
        f32x4 a0 = (f32x4){0,0,0,0}, a1 = (f32x4){0,0,0,0};
        int k0 = kg*16;
        #pragma unroll 4
        for (int k = k0; k < k0 + 16; k++) {
            f32x4 wq = wv[k*8 + j4];
            a0 += sp[k] * wq;
            a1 += sp[512 + k] * wq;
        }
        part[0][kg][j4] = a0; part[1][kg][j4] = a1;
    }
    __syncthreads();
    if (t < 64) {
        int r = t >> 5, f = t & 31;
        float s = 0.f;
        #pragma unroll
        for (int i = 0; i < 32; i++) s += part[r][i][f >> 2][f & 3];
        feat[r][32 + f] = fmaxf(s + cb2[f], 0.f);
    }
    __syncthreads();
    // ---- f3: hidden(2048 bf16) @ cw3(2048x32) ----
    {
        const f32x4* wv = (const f32x4*)cw3;
        f32x4 a0 = (f32x4){0,0,0,0}, a1 = (f32x4){0,0,0,0};
        int k0 = kg*64;
        #pragma unroll 4
        for (int k = k0; k < k0 + 64; k++) {
            f32x4 wq = wv[k*8 + j4];
            float h0 = __bfloat162float(*reinterpret_cast<const bf16*>(&sh[k]));
            float h1 = __bfloat162float(*reinterpret_cast<const bf16*>(&sh[2048 + k]));
            a0 += h0 * wq;
            a1 += h1 * wq;
        }
        part[0][kg][j4] = a0; part[1][kg][j4] = a1;
    }
    __syncthreads();
    if (t < 64) {
        int r = t >> 5, f = t & 31;
        float s = 0.f;
        #pragma unroll
        for (int i = 0; i < 32; i++) s += part[r][i][f >> 2][f & 3];
        feat[r][64 + f] = fmaxf(s + cb3[f], 0.f);
    }
    __syncthreads();
    // ---- fused = relu(feat @ cw4 + cb4): 2 rows x 64 units = 128 threads ----
    if (t < 128) {
        int r = t >> 6, uu = t & 63;
        float s = 0.f;
        #pragma unroll 8
        for (int k = 0; k < 96; k++) s += feat[r][k] * cw4[k*64 + uu];
        fused[r][uu] = fmaxf(s + cb4[uu], 0.f);
    }
    __syncthreads();
    // ---- gating scalar per row: wave r handles row r ----
    if (t < 128) {
        int r = t >> 6, lane = t & 63;
        float v = fused[r][lane] * cw5[lane*2];
        #pragma unroll
        for (int off = 32; off; off >>= 1) v += __shfl_xor(v, off);
        if (lane == 0)
            gsh[r] = 1.f / (1.f + __expf(-(v + cb5[0] - thr[0])));
    }
    __syncthreads();
    #pragma unroll
    for (int idx = t; idx < 1024; idx += 256) {
        int r = idx >> 9, o = idx & 511;
        out0[(size_t)(b0 + r)*512 + o] = sp[r*512 + o] * gsh[r];
    }
}

extern "C" void kernel_launch(void* const* d_in, const int* in_sizes, int n_in,
                              void* d_out, int out_size, void* d_ws, size_t ws_size,
                              hipStream_t stream) {
    const float* x        = (const float*)d_in[0];
    const float* w_       = (const float*)d_in[1];   // (1024, 8192)
    const float* b_bias   = (const float*)d_in[2];
    const float* gate_w   = (const float*)d_in[3];
    const float* gate_b   = (const float*)d_in[4];
    const float* act_w    = (const float*)d_in[5];
    const float* mask     = (const float*)d_in[6];
    const float* mem      = (const float*)d_in[7];   // (2048, 1024)
    const float* att_w    = (const float*)d_in[8];   // (2048, 2048)
    const float* att_b    = (const float*)d_in[9];
    const float* write_w  = (const float*)d_in[10];  // (2048, 1024)
    const float* write_b  = (const float*)d_in[11];
    const float* upd_gate = (const float*)d_in[12];
    const float* out_w    = (const float*)d_in[13];  // (2048, 512)
    const float* out_b    = (const float*)d_in[14];
    const float* cw1 = (const float*)d_in[15]; const float* cb1 = (const float*)d_in[16];
    const float* cw2 = (const float*)d_in[17]; const float* cb2 = (const float*)d_in[18];
    const float* cw3 = (const float*)d_in[19]; const float* cb3 = (const float*)d_in[20];
    const float* cw4 = (const float*)d_in[21]; const float* cb4 = (const float*)d_in[22];
    const float* cw5 = (const float*)d_in[23]; const float* cb5 = (const float*)d_in[24];
    const float* thr = (const float*)d_in[25];

    char* ws = (char*)d_ws;
    float* gate   = (float*)(ws + GATE_OFF);
    float* actw   = (float*)(ws + ACTW_OFF);
    float* uvec   = (float*)(ws + U_OFF);
    float* cmean  = (float*)(ws + CMEAN_OFF);
    float* part   = (float*)(ws + PART_OFF);
    bf16*  hidden = (bf16*)(ws + HIDDEN_OFF);
    bf16*  ratt   = (bf16*)(ws + RATT_OFF);
    bf16*  cand   = (bf16*)(ws + CAND_OFF);
    float* preds  = (float*)(ws + PREDS_OFF);
    float* readv  = (float*)(ws + READ_OFF);
    bf16*  xbf    = (bf16*)(ws + XBF_OFF);
    bf16*  wT     = (bf16*)(ws + WT_OFF);
    bf16*  catT   = (bf16*)(ws + CATT_OFF);
    bf16*  memT   = (bf16*)(ws + MEMT_OFF);

    float* out0 = (float*)d_out;            // (1024, 512)
    float* out1 = out0 + 1024*512;          // (2048, 1024)

    dim3 tb(64, 4);
    // prepass: convert + transpose weights to bf16 N x K
    k_cvt<<<1024, 256, 0, stream>>>(x, xbf);
    k_transpose<<<dim3(128, 16), tb, 0, stream>>>(w_,      wT,             1024, 8192);
    k_transpose<<<dim3(32, 32),  tb, 0, stream>>>(att_w,   catT,           2048, 2048);
    k_transpose<<<dim3(16, 32),  tb, 0, stream>>>(write_w, catT + 2048ull*2048, 2048, 1024);
    k_transpose<<<dim3(8, 32),   tb, 0, stream>>>(out_w,   catT + 3072ull*2048, 2048, 512);
    k_transpose<<<dim3(16, 32),  tb, 0, stream>>>(mem,     memT,           2048, 1024);

    k_gate<<<1024, 256, 0, stream>>>(x, gate_w, gate_b, act_w, gate, actw);

    // G1: hidden = qact((x@w + b)·gate) * mask     [M=1024, N=8192, K=1024]
    gemm_bt<4><<<dim3(64, 8), 256, 0, stream>>>(xbf, wT, 1024,
        b_bias, nullptr, nullptr, nullptr, hidden, nullptr, gate, actw, mask, 2048);
    // G234 fused: [att|write|out] heads            [M=1024, N=3584, K=2048]
    gemm_bt<5><<<dim3(28, 8), 256, 0, stream>>>(hidden, catT, 2048,
        att_b, write_b, out_b, preds, ratt, cand, nullptr, nullptr, nullptr, 0);
    k_softmax<<<1024, 256, 0, stream>>>(ratt);
    // G5: read = ratt @ mem (f32)                  [M=1024, N=1024, K=2048]
    gemm_bt<3><<<dim3(8, 8), 256, 0, stream>>>(ratt, memT, 2048,
        nullptr, nullptr, nullptr, readv, nullptr, nullptr, nullptr, nullptr, nullptr, 1024);

    k_colpart<<<dim3(12, 8), 256, 0, stream>>>(ratt, cand, part);
    k_colfin<<<12, 256, 0, stream>>>(part, upd_gate, uvec, cmean);
    k_newmem<<<8192, 256, 0, stream>>>(mem, uvec, cmean, out1);
    k_critic<<<512, 256, 0, stream>>>(readv, preds, hidden,
        cw1, cb1, cw2, cb2, cw3, cb3, cw4, cb4, cw5, cb5, thr, out0);
}

// Round 11
// 303.831 us; speedup vs baseline: 2.1477x; 1.0943x over previous
//
#include <hip/hip_runtime.h>
#include <hip/hip_bf16.h>
#include <math.h>

typedef __attribute__((ext_vector_type(4))) float f32x4;
typedef __attribute__((ext_vector_type(8))) short s16x8;
typedef __attribute__((ext_vector_type(4))) short s16x4;
typedef __hip_bfloat16 bf16;

#define MB (1024ull*1024ull)
// workspace layout (bytes) — total 53 MB
#define GATE_OFF    (0ull)
#define ACTW_OFF    (16ull*1024)
#define U_OFF       (20ull*1024)
#define CMEAN_OFF   (28ull*1024)
#define PART_OFF    (64ull*1024)
#define HIDDEN_OFF  (1ull*MB)       // bf16 1024x2048 (4MB)
#define RATT_OFF    (5ull*MB)       // bf16 1024x2048 (4MB)
#define CAND_OFF    (9ull*MB)       // bf16 1024x1024 (2MB)
#define PREDS_OFF   (11ull*MB)      // f32 1024x512  (2MB)
#define READ_OFF    (13ull*MB)      // f32 1024x1024 (4MB)
#define XBF_OFF     (17ull*MB)      // bf16 1024x1024 (2MB)
#define WT_OFF      (19ull*MB)      // bf16 8192x1024 (16MB) -> ends 35; READ2 reuses head after G1
#define CATT_OFF    (35ull*MB)      // bf16 3584x2048 (14MB) -> ends 49
#define MEMT_OFF    (49ull*MB)      // bf16 1024x2048 (4MB) -> ends 53
#define READ2_OFF   WT_OFF          // f32 1024x1024 (4MB), alias of dead wT (G5 runs after G1)

__device__ __forceinline__ short f2bf_s(float f) {
    bf16 h = __float2bfloat16(f);
    return *reinterpret_cast<short*>(&h);
}

__device__ __forceinline__ void async_load16(const bf16* g, short* l) {
    __builtin_amdgcn_global_load_lds((const __attribute__((address_space(1))) void*)g,
                                     (__attribute__((address_space(3))) void*)l, 16, 0, 0);
}

__device__ __forceinline__ float fast_tanh(float x) {
    float e2x = __expf(2.f * x);
    return 1.f - 2.f / (e2x + 1.f);
}

// fast 9-way activation mix — __expf algebra only (validated round 9)
__device__ __forceinline__ float qact(float x, const float* w) {
    float ex  = __expf(x);
    float r1  = 1.f / (1.f + ex);
    float sig = 1.f - r1;
    float em1 = ex - 1.f;
    float elu = x > 0.f ? x : em1;
    float e2x = ex * ex;
    float th  = 1.f - 2.f / (e2x + 1.f);
    float rel = fmaxf(x, 0.f);
    float silu = x * sig;
    float u   = 0.7978845608028654f * (x + 0.044715f * x * x * x);
    float e2u = __expf(2.f * u);
    float gel = x * (1.f - 1.f / (e2u + 1.f));
    float sel = 1.0507009873554805f * (x > 0.f ? x : 1.6732632423543772f * em1);
    float t   = 1.f + ex;
    float t2  = t * t;
    float mish = x * (1.f - 2.f / (t2 + 1.f));
    return w[0]*sig + w[1]*elu + w[2]*th + w[3]*rel + w[4]*silu
         + w[5]*gel + w[6]*sel + w[7]*mish + w[8]*x;
}

// ---------------- fp32 (R x C) -> bf16 (C x R) transpose, 64x64 tiles ----------------
__global__ __launch_bounds__(256) void k_transpose(const float* __restrict__ in,
                                                   bf16* __restrict__ out, int R, int C) {
    __shared__ short tile[64][66];
    int k0 = blockIdx.y*64, n0 = blockIdx.x*64;
    int tx = threadIdx.x, ty = threadIdx.y;     // (64,4)
    #pragma unroll
    for (int j = 0; j < 16; j++) {
        int k = ty + j*4;
        tile[tx][k] = f2bf_s(in[(size_t)(k0 + k)*C + n0 + tx]);
    }
    __syncthreads();
    int t = ty*64 + tx;
    int kp = t & 31, nrow = t >> 5;
    #pragma unroll
    for (int jj = 0; jj < 8; jj++) {
        int n = nrow + jj*8;
        unsigned lo = (unsigned short)tile[n][kp*2];
        unsigned hi = (unsigned short)tile[n][kp*2 + 1];
        *reinterpret_cast<unsigned*>(&out[(size_t)(n0 + n)*R + k0 + kp*2]) = lo | (hi << 16);
    }
}

// ---------------- fp32 -> bf16 flat convert ----------------
__global__ __launch_bounds__(256) void k_cvt(const float* __restrict__ in,
                                             bf16* __restrict__ out) {
    int i = blockIdx.x*256 + threadIdx.x;
    f32x4 v = ((const f32x4*)in)[i];
    s16x4 o;
    #pragma unroll
    for (int j = 0; j < 4; j++) o[j] = f2bf_s(v[j]);
    ((s16x4*)out)[i] = o;
}

// ---------------- gate softmax + act-weight softmax (all f32) ----------------
__global__ __launch_bounds__(256) void k_gate(const float* __restrict__ x,
                                              const float* __restrict__ gw,
                                              const float* __restrict__ gb,
                                              const float* __restrict__ aw_in,
                                              float* __restrict__ gate,
                                              float* __restrict__ actw) {
    int b = blockIdx.x, t = threadIdx.x, w = t >> 6, lane = t & 63;
    __shared__ float l[4];
    float s = 0.f;
    for (int k = lane; k < 1024; k += 64)
        s += x[(size_t)b*1024 + k] * gw[k*4 + w];
    #pragma unroll
    for (int off = 32; off; off >>= 1) s += __shfl_xor(s, off);
    if (lane == 0) l[w] = s + gb[w];
    __syncthreads();
    if (t == 0) {
        float m = fmaxf(fmaxf(l[0], l[1]), fmaxf(l[2], l[3]));
        float e0 = __expf(l[0]-m), e1 = __expf(l[1]-m), e2 = __expf(l[2]-m), e3 = __expf(l[3]-m);
        float inv = 1.f / (e0+e1+e2+e3);
        gate[b*4+0] = e0*inv; gate[b*4+1] = e1*inv;
        gate[b*4+2] = e2*inv; gate[b*4+3] = e3*inv;
    }
    if (b == 0 && t == 64) {
        float a[9]; float m = -1e30f;
        for (int i = 0; i < 9; i++) { a[i] = aw_in[i]; m = fmaxf(m, a[i]); }
        float ss = 0.f;
        for (int i = 0; i < 9; i++) { a[i] = __expf(a[i]-m); ss += a[i]; }
        float inv = 1.f / ss;
        for (int i = 0; i < 9; i++) actw[i] = a[i]*inv;
    }
}

// ---------------- GEMM (BT): C = A(MxK) @ Bt(NxK)^T, TMx128 tile, BK=32 ----------------
// TM in {64,128}. Occupancy fix (round 11): TM=64 doubles block count (latency-bound fix).
// Split-K via gridDim.z: A/Bt advance by kOffset*z; MODE 3 writes outF (z=0) / outF2 (z=1).
template <int MODE, int TM>
__global__ __launch_bounds__(256, 2) void gemm_bt(
        const bf16* __restrict__ A, const bf16* __restrict__ Bt,
        int K, int lda, int ldb, int kOffset,
        const float* __restrict__ bias, const float* __restrict__ bias2,
        const float* __restrict__ bias3,
        float* __restrict__ outF, float* __restrict__ outF2,
        bf16* __restrict__ outH, bf16* __restrict__ outH2,
        const float* __restrict__ gate, const float* __restrict__ actw,
        const float* __restrict__ mask, int outStride) {
    constexpr int MI = TM / 32;
    __shared__ __align__(16) union SMem {
        struct { short a[TM*32]; short b[128*32]; } tl;
        float z[TM*32];
    } sm;
    int t = threadIdx.x, lane = t & 63;
    int rowBase = blockIdx.y * TM, colBase = blockIdx.x * 128;
    int lm = lane & 15, lq = lane >> 4;
    int w = t >> 6;
    int qm = (w >> 1) * (TM/2), qn = (w & 1) * 64;

    A  += (size_t)kOffset * blockIdx.z;
    Bt += (size_t)kOffset * blockIdx.z;

    f32x4 acc[MI][4];
    #pragma unroll
    for (int i = 0; i < MI; i++)
        #pragma unroll
        for (int j = 0; j < 4; j++) acc[i][j] = (f32x4){0.f, 0.f, 0.f, 0.f};

    // B staging (128 rows): chunks c = w*128 + lane (+64)
    int cb0 = w*128 + lane, cb1 = cb0 + 64;
    int rb0 = cb0 >> 2, kb0 = (cb0 & 3) * 8;
    int rb1 = cb1 >> 2, kb1 = (cb1 & 3) * 8;
    short* dstB0 = sm.tl.b + w*1024;
    short* dstB1 = sm.tl.b + w*1024 + 512;
    // A staging
    int ca0 = (TM == 128) ? (w*128 + lane) : (w*64 + lane);
    int ra0 = ca0 >> 2, ka0 = (ca0 & 3) * 8;
    int ra1 = (ca0 + 64) >> 2, ka1 = ((ca0 + 64) & 3) * 8;   // used only for TM=128
    short* dstA0 = sm.tl.a + ((TM == 128) ? w*1024 : w*512);
    short* dstA1 = sm.tl.a + w*1024 + 512;

    for (int k0 = 0; k0 < K; k0 += 32) {
        __syncthreads();
        async_load16(A + (size_t)(rowBase + ra0)*lda + k0 + ka0, dstA0);
        if (TM == 128)
            async_load16(A + (size_t)(rowBase + ra1)*lda + k0 + ka1, dstA1);
        async_load16(Bt + (size_t)(colBase + rb0)*ldb + k0 + kb0, dstB0);
        async_load16(Bt + (size_t)(colBase + rb1)*ldb + k0 + kb1, dstB1);
        __syncthreads();
        s16x8 af[MI], bfr[4];
        #pragma unroll
        for (int mi = 0; mi < MI; mi++)
            af[mi] = *reinterpret_cast<const s16x8*>(sm.tl.a + (qm + mi*16 + lm)*32 + lq*8);
        #pragma unroll
        for (int ni = 0; ni < 4; ni++)
            bfr[ni] = *reinterpret_cast<const s16x8*>(sm.tl.b + (qn + ni*16 + lm)*32 + lq*8);
        #pragma unroll
        for (int mi = 0; mi < MI; mi++)
            #pragma unroll
            for (int ni = 0; ni < 4; ni++)
                acc[mi][ni] = __builtin_amdgcn_mfma_f32_16x16x32_bf16(af[mi], bfr[ni], acc[mi][ni], 0, 0, 0);
    }

    if (MODE == 4) {
        __syncthreads();
        #pragma unroll
        for (int mi = 0; mi < MI; mi++) {
            int rowl0 = qm + mi*16 + lq*4;
            #pragma unroll
            for (int ni = 0; ni < 4; ni++) {
                int col = colBase + qn + ni*16 + lm;
                int n = col & 3;
                float bb = bias[col];
                f32x4 v = acc[mi][ni];
                #pragma unroll
                for (int r = 0; r < 4; r++) v[r] = (v[r] + bb) * gate[(rowBase + rowl0 + r)*4 + n];
                #pragma unroll
                for (int r = 0; r < 4; r++) v[r] += __shfl_xor(v[r], 1);
                #pragma unroll
                for (int r = 0; r < 4; r++) v[r] += __shfl_xor(v[r], 2);
                if ((lane & 3) == 0) {
                    int ul = ((w & 1) << 4) + ni*4 + (lm >> 2);
                    #pragma unroll
                    for (int r = 0; r < 4; r++)
                        sm.z[(rowl0 + r)*32 + ul] = v[r];
                }
            }
        }
        __syncthreads();
        float aw[9];
        #pragma unroll
        for (int i = 0; i < 9; i++) aw[i] = actw[i];
        int u0 = colBase >> 2;
        #pragma unroll
        for (int i = 0; i < TM/8; i++) {
            int idx = t + i*256;
            int row = idx >> 5, ul = idx & 31;
            int ug = u0 + ul;
            float zz = sm.z[idx];
            outH[(size_t)(rowBase + row)*outStride + ug] = __float2bfloat16(qact(zz, aw) * mask[ug]);
        }
    } else if (MODE == 5) {
        #pragma unroll
        for (int mi = 0; mi < MI; mi++) {
            int row0 = rowBase + qm + mi*16 + lq*4;
            #pragma unroll
            for (int ni = 0; ni < 4; ni++) {
                int col = colBase + qn + ni*16 + lm;
                if (col < 2048) {
                    float bb = bias[col];
                    #pragma unroll
                    for (int r = 0; r < 4; r++)
                        outH[(size_t)(row0 + r)*2048 + col] = __float2bfloat16(acc[mi][ni][r] + bb);
                } else if (col < 3072) {
                    int c = col - 2048;
                    float bb = bias2[c];
                    #pragma unroll
                    for (int r = 0; r < 4; r++)
                        outH2[(size_t)(row0 + r)*1024 + c] = __float2bfloat16(fast_tanh(acc[mi][ni][r] + bb));
                } else {
                    int c = col - 3072;
                    float bb = bias3[c];
                    #pragma unroll
                    for (int r = 0; r < 4; r++)
                        outF[(size_t)(row0 + r)*512 + c] = acc[mi][ni][r] + bb;
                }
            }
        }
    } else {  // MODE 3 (split-K partial)
        float* of = blockIdx.z ? outF2 : outF;
        #pragma unroll
        for (int mi = 0; mi < MI; mi++) {
            int row0 = rowBase + qm + mi*16 + lq*4;
            #pragma unroll
            for (int ni = 0; ni < 4; ni++) {
                int col = colBase + qn + ni*16 + lm;
                #pragma unroll
                for (int r = 0; r < 4; r++)
                    of[(size_t)(row0 + r)*outStride + col] = acc[mi][ni][r];
            }
        }
    }
}

// ---------------- in-place row softmax over 2048 cols (bf16 buffer) ----------------
__global__ __launch_bounds__(256) void k_softmax(bf16* __restrict__ ratt) {
    int b = blockIdx.x, t = threadIdx.x, w = t >> 6, lane = t & 63;
    __shared__ float red[8];
    bf16* row = ratt + (size_t)b*2048;
    float v[8];
    float mx = -1e30f;
    #pragma unroll
    for (int j = 0; j < 8; j++) {
        v[j] = __bfloat162float(row[t + j*256]);
        mx = fmaxf(mx, v[j]);
    }
    #pragma unroll
    for (int off = 32; off; off >>= 1) mx = fmaxf(mx, __shfl_xor(mx, off));
    if (lane == 0) red[w] = mx;
    __syncthreads();
    mx = fmaxf(fmaxf(red[0], red[1]), fmaxf(red[2], red[3]));
    float s = 0.f;
    #pragma unroll
    for (int j = 0; j < 8; j++) { v[j] = __expf(v[j] - mx); s += v[j]; }
    #pragma unroll
    for (int off = 32; off; off >>= 1) s += __shfl_xor(s, off);
    if (lane == 0) red[4 + w] = s;
    __syncthreads();
    float inv = 1.f / (red[4] + red[5] + red[6] + red[7]);
    #pragma unroll
    for (int j = 0; j < 8; j++)
        row[t + j*256] = __float2bfloat16(v[j] * inv);
}

// ---------------- column-mean partials ----------------
__global__ __launch_bounds__(256) void k_colpart(const bf16* __restrict__ ratt,
                                                 const bf16* __restrict__ cand,
                                                 float* __restrict__ part) {
    int ct = blockIdx.x, rc = blockIdx.y, t = threadIdx.x;
    int col = ct*256 + t;
    const bf16* src; int stride, c;
    if (ct < 8) { src = ratt; stride = 2048; c = col; }
    else        { src = cand; stride = 1024; c = col - 2048; }
    float s = 0.f;
    int r0 = rc*128;
    for (int r = 0; r < 128; r++)
        s += __bfloat162float(src[(size_t)(r0 + r)*stride + c]);
    part[rc*3072 + col] = s;
}

__global__ __launch_bounds__(256) void k_colfin(const float* __restrict__ part,
                                                const float* __restrict__ update_gate,
                                                float* __restrict__ u,
                                                float* __restrict__ cmean) {
    int col = blockIdx.x*256 + threadIdx.x;
    float s = 0.f;
    #pragma unroll
    for (int rc = 0; rc < 8; rc++) s += part[rc*3072 + col];
    s *= (1.f/1024.f);
    if (col < 2048) u[col] = s * update_gate[col];
    else            cmean[col - 2048] = s;
}

// ---------------- new_mem blend (f32 out) ----------------
__global__ __launch_bounds__(256) void k_newmem(const float* __restrict__ mem,
                                                const float* __restrict__ u,
                                                const float* __restrict__ cmean,
                                                float* __restrict__ out1) {
    int idx = blockIdx.x*256 + threadIdx.x;
    int m = idx >> 10, d = idx & 1023;
    float um = u[m];
    out1[idx] = mem[idx] * (1.f - um) + um * cmean[d];
}

// ---------------- critic: 2 rows/block, f32x4 weight loads (round-10 validated) ----------------
__global__ __launch_bounds__(256) void k_critic(
        const float* __restrict__ readv, const float* __restrict__ readv2,
        const float* __restrict__ preds, const bf16* __restrict__ hidden,
        const float* cw1, const float* cb1, const float* cw2, const float* cb2,
        const float* cw3, const float* cb3, const float* cw4, const float* cb4,
        const float* cw5, const float* cb5, const float* thr,
        float* __restrict__ out0) {
    __shared__ __align__(16) float sx[2*1024];
    __shared__ __align__(16) float sp[2*512];
    __shared__ __align__(16) short sh[2*2048];
    __shared__ __align__(16) f32x4 part[2][32][8];
    __shared__ float feat[2][96];
    __shared__ float fused[2][64];
    __shared__ float gsh[2];
    int b0 = blockIdx.x * 2, t = threadIdx.x;
    int j4 = t & 7, kg = t >> 3;

    // stage 2 rows of each activation; read = split-K partial sum
    ((f32x4*)sx)[t]       = ((const f32x4*)(readv + (size_t)b0*1024))[t]
                          + ((const f32x4*)(readv2 + (size_t)b0*1024))[t];
    ((f32x4*)sx)[t + 256] = ((const f32x4*)(readv + (size_t)b0*1024))[t + 256]
                          + ((const f32x4*)(readv2 + (size_t)b0*1024))[t + 256];
    ((f32x4*)sp)[t]       = ((const f32x4*)(preds + (size_t)b0*512))[t];
    ((s16x8*)sh)[t]       = ((const s16x8*)(hidden + (size_t)b0*2048))[t];
    ((s16x8*)sh)[t + 256] = ((const s16x8*)(hidden + (size_t)b0*2048))[t + 256];
    __syncthreads();

    {
        const f32x4* wv = (const f32x4*)cw1;
        f32x4 a0 = (f32x4){0,0,0,0}, a1 = (f32x4){0,0,0,0};
        int k0 = kg*32;
        #pragma unroll 4
        for (int k = k0; k < k0 + 32; k++) {
            f32x4 wq = wv[k*8 + j4];
            a0 += sx[k] * wq;
            a1 += sx[1024 + k] * wq;
        }
        part[0][kg][j4] = a0; part[1][kg][j4] = a1;
    }
    __syncthreads();
    if (t < 64) {
        int r = t >> 5, f = t & 31;
        float s = 0.f;
        #pragma unroll
        for (int i = 0; i < 32; i++) s += part[r][i][f >> 2][f & 3];
        feat[r][f] = fmaxf(s + cb1[f], 0.f);
    }
    __syncthreads();
    {
        const f32x4* wv = (const f32x4*)cw2;
        f32x4 a0 = (f32x4){0,0,0,0}, a1 = (f32x4){0,0,0,0};
        int k0 = kg*16;
        #pragma unroll 4
        for (int k = k0; k < k0 + 16; k++) {
            f32x4 wq = wv[k*8 + j4];
            a0 += sp[k] * wq;
            a1 += sp[512 + k] * wq;
        }
        part[0][kg][j4] = a0; part[1][kg][j4] = a1;
    }
    __syncthreads();
    if (t < 64) {
        int r = t >> 5, f = t & 31;
        float s = 0.f;
        #pragma unroll
        for (int i = 0; i < 32; i++) s += part[r][i][f >> 2][f & 3];
        feat[r][32 + f] = fmaxf(s + cb2[f], 0.f);
    }
    __syncthreads();
    {
        const f32x4* wv = (const f32x4*)cw3;
        f32x4 a0 = (f32x4){0,0,0,0}, a1 = (f32x4){0,0,0,0};
        int k0 = kg*64;
        #pragma unroll 4
        for (int k = k0; k < k0 + 64; k++) {
            f32x4 wq = wv[k*8 + j4];
            float h0 = __bfloat162float(*reinterpret_cast<const bf16*>(&sh[k]));
            float h1 = __bfloat162float(*reinterpret_cast<const bf16*>(&sh[2048 + k]));
            a0 += h0 * wq;
            a1 += h1 * wq;
        }
        part[0][kg][j4] = a0; part[1][kg][j4] = a1;
    }
    __syncthreads();
    if (t < 64) {
        int r = t >> 5, f = t & 31;
        float s = 0.f;
        #pragma unroll
        for (int i = 0; i < 32; i++) s += part[r][i][f >> 2][f & 3];
        feat[r][64 + f] = fmaxf(s + cb3[f], 0.f);
    }
    __syncthreads();
    if (t < 128) {
        int r = t >> 6, uu = t & 63;
        float s = 0.f;
        #pragma unroll 8
        for (int k = 0; k < 96; k++) s += feat[r][k] * cw4[k*64 + uu];
        fused[r][uu] = fmaxf(s + cb4[uu], 0.f);
    }
    __syncthreads();
    if (t < 128) {
        int r = t >> 6, lane = t & 63;
        float v = fused[r][lane] * cw5[lane*2];
        #pragma unroll
        for (int off = 32; off; off >>= 1) v += __shfl_xor(v, off);
        if (lane == 0)
            gsh[r] = 1.f / (1.f + __expf(-(v + cb5[0] - thr[0])));
    }
    __syncthreads();
    #pragma unroll
    for (int idx = t; idx < 1024; idx += 256) {
        int r = idx >> 9, o = idx & 511;
        out0[(size_t)(b0 + r)*512 + o] = sp[r*512 + o] * gsh[r];
    }
}

extern "C" void kernel_launch(void* const* d_in, const int* in_sizes, int n_in,
                              void* d_out, int out_size, void* d_ws, size_t ws_size,
                              hipStream_t stream) {
    const float* x        = (const float*)d_in[0];
    const float* w_       = (const float*)d_in[1];
    const float* b_bias   = (const float*)d_in[2];
    const float* gate_w   = (const float*)d_in[3];
    const float* gate_b   = (const float*)d_in[4];
    const float* act_w    = (const float*)d_in[5];
    const float* mask     = (const float*)d_in[6];
    const float* mem      = (const float*)d_in[7];
    const float* att_w    = (const float*)d_in[8];
    const float* att_b    = (const float*)d_in[9];
    const float* write_w  = (const float*)d_in[10];
    const float* write_b  = (const float*)d_in[11];
    const float* upd_gate = (const float*)d_in[12];
    const float* out_w    = (const float*)d_in[13];
    const float* out_b    = (const float*)d_in[14];
    const float* cw1 = (const float*)d_in[15]; const float* cb1 = (const float*)d_in[16];
    const float* cw2 = (const float*)d_in[17]; const float* cb2 = (const float*)d_in[18];
    const float* cw3 = (const float*)d_in[19]; const float* cb3 = (const float*)d_in[20];
    const float* cw4 = (const float*)d_in[21]; const float* cb4 = (const float*)d_in[22];
    const float* cw5 = (const float*)d_in[23]; const float* cb5 = (const float*)d_in[24];
    const float* thr = (const float*)d_in[25];

    char* ws = (char*)d_ws;
    float* gate   = (float*)(ws + GATE_OFF);
    float* actw   = (float*)(ws + ACTW_OFF);
    float* uvec   = (float*)(ws + U_OFF);
    float* cmean  = (float*)(ws + CMEAN_OFF);
    float* part   = (float*)(ws + PART_OFF);
    bf16*  hidden = (bf16*)(ws + HIDDEN_OFF);
    bf16*  ratt   = (bf16*)(ws + RATT_OFF);
    bf16*  cand   = (bf16*)(ws + CAND_OFF);
    float* preds  = (float*)(ws + PREDS_OFF);
    float* readv  = (float*)(ws + READ_OFF);
    float* readv2 = (float*)(ws + READ2_OFF);   // aliases wT head (dead after G1)
    bf16*  xbf    = (bf16*)(ws + XBF_OFF);
    bf16*  wT     = (bf16*)(ws + WT_OFF);
    bf16*  catT   = (bf16*)(ws + CATT_OFF);
    bf16*  memT   = (bf16*)(ws + MEMT_OFF);

    float* out0 = (float*)d_out;            // (1024, 512)
    float* out1 = out0 + 1024*512;          // (2048, 1024)

    dim3 tb(64, 4);
    k_cvt<<<1024, 256, 0, stream>>>(x, xbf);
    k_transpose<<<dim3(128, 16), tb, 0, stream>>>(w_,      wT,                  1024, 8192);
    k_transpose<<<dim3(32, 32),  tb, 0, stream>>>(att_w,   catT,                2048, 2048);
    k_transpose<<<dim3(16, 32),  tb, 0, stream>>>(write_w, catT + 2048ull*2048, 2048, 1024);
    k_transpose<<<dim3(8, 32),   tb, 0, stream>>>(out_w,   catT + 3072ull*2048, 2048, 512);
    k_transpose<<<dim3(16, 32),  tb, 0, stream>>>(mem,     memT,                2048, 1024);

    k_gate<<<1024, 256, 0, stream>>>(x, gate_w, gate_b, act_w, gate, actw);

    // G1: hidden = qact((x@w + b)·gate) * mask     [M=1024, N=8192, K=1024] — 1024 blocks
    gemm_bt<4, 64><<<dim3(64, 16), 256, 0, stream>>>(xbf, wT, 1024, 1024, 1024, 0,
        b_bias, nullptr, nullptr, nullptr, nullptr, hidden, nullptr, gate, actw, mask, 2048);
    // G234 fused: [att|write|out] heads            [M=1024, N=3584, K=2048] — 448 blocks
    gemm_bt<5, 64><<<dim3(28, 16), 256, 0, stream>>>(hidden, catT, 2048, 2048, 2048, 0,
        att_b, write_b, out_b, preds, nullptr, ratt, cand, nullptr, nullptr, nullptr, 0);
    k_softmax<<<1024, 256, 0, stream>>>(ratt);
    // G5: read = ratt @ mem, split-K=2             [M=1024, N=1024, K=2x1024] — 256 blocks
    gemm_bt<3, 64><<<dim3(8, 16, 2), 256, 0, stream>>>(ratt, memT, 1024, 2048, 2048, 1024,
        nullptr, nullptr, nullptr, readv, readv2, nullptr, nullptr, nullptr, nullptr, nullptr, 1024);

    k_colpart<<<dim3(12, 8), 256, 0, stream>>>(ratt, cand, part);
    k_colfin<<<12, 256, 0, stream>>>(part, upd_gate, uvec, cmean);
    k_newmem<<<8192, 256, 0, stream>>>(mem, uvec, cmean, out1);
    k_critic<<<512, 256, 0, stream>>>(readv, readv2, preds, hidden,
        cw1, cb1, cw2, cb2, cw3, cb3, cw4, cb4, cw5, cb5, thr, out0);
}

// Round 12
// 268.818 us; speedup vs baseline: 2.4274x; 1.1302x over previous
//
#include <hip/hip_runtime.h>
#include <hip/hip_bf16.h>
#include <math.h>

typedef __attribute__((ext_vector_type(4))) float f32x4;
typedef __attribute__((ext_vector_type(8))) short s16x8;
typedef __attribute__((ext_vector_type(4))) short s16x4;
typedef __hip_bfloat16 bf16;

#define MB (1024ull*1024ull)
// workspace layout (bytes) — total 53 MB
#define GATE_OFF    (0ull)
#define ACTW_OFF    (16ull*1024)
#define U_OFF       (20ull*1024)
#define CMEAN_OFF   (28ull*1024)
#define PART_OFF    (64ull*1024)
#define HIDDEN_OFF  (1ull*MB)
#define RATT_OFF    (5ull*MB)
#define CAND_OFF    (9ull*MB)
#define PREDS_OFF   (11ull*MB)
#define READ_OFF    (13ull*MB)
#define XBF_OFF     (17ull*MB)
#define WT_OFF      (19ull*MB)      // bf16 8192x1024 (16MB); READ2 aliases head after G1
#define CATT_OFF    (35ull*MB)      // bf16 3584x2048 (14MB)
#define MEMT_OFF    (49ull*MB)      // bf16 1024x2048 (4MB)
#define READ2_OFF   WT_OFF

__device__ __forceinline__ short f2bf_s(float f) {
    bf16 h = __float2bfloat16(f);
    return *reinterpret_cast<short*>(&h);
}

__device__ __forceinline__ void async_load16(const bf16* g, short* l) {
    __builtin_amdgcn_global_load_lds((const __attribute__((address_space(1))) void*)g,
                                     (__attribute__((address_space(3))) void*)l, 16, 0, 0);
}

__device__ __forceinline__ float fast_tanh(float x) {
    float e2x = __expf(2.f * x);
    return 1.f - 2.f / (e2x + 1.f);
}

// fast 9-way activation mix — __expf algebra only (validated round 9)
__device__ __forceinline__ float qact(float x, const float* w) {
    float ex  = __expf(x);
    float r1  = 1.f / (1.f + ex);
    float sig = 1.f - r1;
    float em1 = ex - 1.f;
    float elu = x > 0.f ? x : em1;
    float e2x = ex * ex;
    float th  = 1.f - 2.f / (e2x + 1.f);
    float rel = fmaxf(x, 0.f);
    float silu = x * sig;
    float u   = 0.7978845608028654f * (x + 0.044715f * x * x * x);
    float e2u = __expf(2.f * u);
    float gel = x * (1.f - 1.f / (e2u + 1.f));
    float sel = 1.0507009873554805f * (x > 0.f ? x : 1.6732632423543772f * em1);
    float t   = 1.f + ex;
    float t2  = t * t;
    float mish = x * (1.f - 2.f / (t2 + 1.f));
    return w[0]*sig + w[1]*elu + w[2]*th + w[3]*rel + w[4]*silu
         + w[5]*gel + w[6]*sel + w[7]*mish + w[8]*x;
}

// ---------------- fused prepass: cvt + gate + 5 transposes, one dispatch ----------------
// block ranges: [0,1024) cvt; [1024,2048) gate; then transposes (flat bx/by per job).
__device__ __forceinline__ void do_transpose(const float* __restrict__ in,
                                             bf16* __restrict__ out, int R, int C,
                                             int bx, int by, int t) {
    __shared__ short tile[64][66];
    int k0 = by*64, n0 = bx*64;
    int tx = t & 63, ty = t >> 6;
    #pragma unroll
    for (int j = 0; j < 16; j++) {
        int k = ty + j*4;
        tile[tx][k] = f2bf_s(in[(size_t)(k0 + k)*C + n0 + tx]);
    }
    __syncthreads();
    int kp = t & 31, nrow = t >> 5;
    #pragma unroll
    for (int jj = 0; jj < 8; jj++) {
        int n = nrow + jj*8;
        unsigned lo = (unsigned short)tile[n][kp*2];
        unsigned hi = (unsigned short)tile[n][kp*2 + 1];
        *reinterpret_cast<unsigned*>(&out[(size_t)(n0 + n)*R + k0 + kp*2]) = lo | (hi << 16);
    }
}

__global__ __launch_bounds__(256) void k_prepass(
        const float* __restrict__ x, bf16* __restrict__ xbf,
        const float* __restrict__ gw, const float* __restrict__ gb,
        const float* __restrict__ aw_in,
        float* __restrict__ gate, float* __restrict__ actw,
        const float* __restrict__ w_, bf16* __restrict__ wT,
        const float* __restrict__ att_w, const float* __restrict__ write_w,
        const float* __restrict__ out_w, bf16* __restrict__ catT,
        const float* __restrict__ mem, bf16* __restrict__ memT) {
    int blk = blockIdx.x, t = threadIdx.x;
    if (blk < 1024) {
        // x -> bf16
        int i = blk*256 + t;
        f32x4 v = ((const f32x4*)x)[i];
        s16x4 o;
        #pragma unroll
        for (int j = 0; j < 4; j++) o[j] = f2bf_s(v[j]);
        ((s16x4*)xbf)[i] = o;
        // act-weight softmax (once)
        if (blk == 0 && t == 64) {
            float a[9]; float m = -1e30f;
            for (int i2 = 0; i2 < 9; i2++) { a[i2] = aw_in[i2]; m = fmaxf(m, a[i2]); }
            float ss = 0.f;
            for (int i2 = 0; i2 < 9; i2++) { a[i2] = __expf(a[i2]-m); ss += a[i2]; }
            float inv = 1.f / ss;
            for (int i2 = 0; i2 < 9; i2++) actw[i2] = a[i2]*inv;
        }
    } else if (blk < 2048) {
        // branch-gate softmax for row b
        int b = blk - 1024, w = t >> 6, lane = t & 63;
        __shared__ float l[4];
        float s = 0.f;
        for (int k = lane; k < 1024; k += 64)
            s += x[(size_t)b*1024 + k] * gw[k*4 + w];
        #pragma unroll
        for (int off = 32; off; off >>= 1) s += __shfl_xor(s, off);
        if (lane == 0) l[w] = s + gb[w];
        __syncthreads();
        if (t == 0) {
            float m = fmaxf(fmaxf(l[0], l[1]), fmaxf(l[2], l[3]));
            float e0 = __expf(l[0]-m), e1 = __expf(l[1]-m), e2 = __expf(l[2]-m), e3 = __expf(l[3]-m);
            float inv = 1.f / (e0+e1+e2+e3);
            gate[b*4+0] = e0*inv; gate[b*4+1] = e1*inv;
            gate[b*4+2] = e2*inv; gate[b*4+3] = e3*inv;
        }
    } else if (blk < 4096) {
        int rel = blk - 2048;                       // w_: 1024x8192, gridX=128
        do_transpose(w_, wT, 1024, 8192, rel & 127, rel >> 7, t);
    } else if (blk < 5120) {
        int rel = blk - 4096;                       // att: 2048x2048, gridX=32
        do_transpose(att_w, catT, 2048, 2048, rel & 31, rel >> 5, t);
    } else if (blk < 5632) {
        int rel = blk - 5120;                       // write: 2048x1024, gridX=16
        do_transpose(write_w, catT + 2048ull*2048, 2048, 1024, rel & 15, rel >> 4, t);
    } else if (blk < 5888) {
        int rel = blk - 5632;                       // out: 2048x512, gridX=8
        do_transpose(out_w, catT + 3072ull*2048, 2048, 512, rel & 7, rel >> 3, t);
    } else {
        int rel = blk - 5888;                       // mem: 2048x1024, gridX=16
        do_transpose(mem, memT, 2048, 1024, rel & 15, rel >> 4, t);
    }
}

// ---------------- GEMM (BT): C = A(MxK) @ Bt(NxK)^T, TMx128 tile, BK=32 ----------------
// Round 12: single-barrier double-buffered K-loop — prefetch k+1 into alt buffer after
// the barrier so the barrier's vmcnt drain waits on loads a full compute-phase old.
template <int MODE, int TM>
__global__ __launch_bounds__(256, 2) void gemm_bt(
        const bf16* __restrict__ A, const bf16* __restrict__ Bt,
        int K, int lda, int ldb, int kOffset,
        const float* __restrict__ bias, const float* __restrict__ bias2,
        const float* __restrict__ bias3,
        float* __restrict__ outF, float* __restrict__ outF2,
        bf16* __restrict__ outH, bf16* __restrict__ outH2,
        const float* __restrict__ gate, const float* __restrict__ actw,
        const float* __restrict__ mask, int outStride) {
    constexpr int MI = TM / 32;
    __shared__ __align__(16) union SMem {
        struct { short a[2][TM*32]; short b[2][128*32]; } tl;
        float z[TM*32];
    } sm;
    int t = threadIdx.x, lane = t & 63;
    int rowBase = blockIdx.y * TM, colBase = blockIdx.x * 128;
    int lm = lane & 15, lq = lane >> 4;
    int w = t >> 6;
    int qm = (w >> 1) * (TM/2), qn = (w & 1) * 64;

    A  += (size_t)kOffset * blockIdx.z;
    Bt += (size_t)kOffset * blockIdx.z;

    f32x4 acc[MI][4];
    #pragma unroll
    for (int i = 0; i < MI; i++)
        #pragma unroll
        for (int j = 0; j < 4; j++) acc[i][j] = (f32x4){0.f, 0.f, 0.f, 0.f};

    // B staging: chunks c = w*128 + lane (+64)
    int cb0 = w*128 + lane, cb1 = cb0 + 64;
    int rb0 = cb0 >> 2, kb0 = (cb0 & 3) * 8;
    int rb1 = cb1 >> 2, kb1 = (cb1 & 3) * 8;
    // A staging
    int ca0 = (TM == 128) ? (w*128 + lane) : (w*64 + lane);
    int ra0 = ca0 >> 2, ka0 = (ca0 & 3) * 8;
    int ra1 = (ca0 + 64) >> 2, ka1 = ((ca0 + 64) & 3) * 8;   // TM=128 only

    auto issueLoads = [&](int k0, int ib) {
        short* bA = sm.tl.a[ib];
        short* bB = sm.tl.b[ib];
        async_load16(A + (size_t)(rowBase + ra0)*lda + k0 + ka0,
                     bA + ((TM == 128) ? w*1024 : w*512));
        if (TM == 128)
            async_load16(A + (size_t)(rowBase + ra1)*lda + k0 + ka1, bA + w*1024 + 512);
        async_load16(Bt + (size_t)(colBase + rb0)*ldb + k0 + kb0, bB + w*1024);
        async_load16(Bt + (size_t)(colBase + rb1)*ldb + k0 + kb1, bB + w*1024 + 512);
    };

    issueLoads(0, 0);
    int ib = 0;
    for (int k0 = 0; k0 < K; k0 += 32) {
        __syncthreads();                    // drains vmcnt: buf[ib] ready; buf[ib^1] free
        if (k0 + 32 < K) issueLoads(k0 + 32, ib ^ 1);
        const short* cA = sm.tl.a[ib];
        const short* cB = sm.tl.b[ib];
        s16x8 af[MI], bfr[4];
        #pragma unroll
        for (int mi = 0; mi < MI; mi++)
            af[mi] = *reinterpret_cast<const s16x8*>(cA + (qm + mi*16 + lm)*32 + lq*8);
        #pragma unroll
        for (int ni = 0; ni < 4; ni++)
            bfr[ni] = *reinterpret_cast<const s16x8*>(cB + (qn + ni*16 + lm)*32 + lq*8);
        #pragma unroll
        for (int mi = 0; mi < MI; mi++)
            #pragma unroll
            for (int ni = 0; ni < 4; ni++)
                acc[mi][ni] = __builtin_amdgcn_mfma_f32_16x16x32_bf16(af[mi], bfr[ni], acc[mi][ni], 0, 0, 0);
        ib ^= 1;
    }

    if (MODE == 4) {
        __syncthreads();   // all tile reads done; safe to overlay sm.z
        #pragma unroll
        for (int mi = 0; mi < MI; mi++) {
            int rowl0 = qm + mi*16 + lq*4;
            #pragma unroll
            for (int ni = 0; ni < 4; ni++) {
                int col = colBase + qn + ni*16 + lm;
                int n = col & 3;
                float bb = bias[col];
                f32x4 v = acc[mi][ni];
                #pragma unroll
                for (int r = 0; r < 4; r++) v[r] = (v[r] + bb) * gate[(rowBase + rowl0 + r)*4 + n];
                #pragma unroll
                for (int r = 0; r < 4; r++) v[r] += __shfl_xor(v[r], 1);
                #pragma unroll
                for (int r = 0; r < 4; r++) v[r] += __shfl_xor(v[r], 2);
                if ((lane & 3) == 0) {
                    int ul = ((w & 1) << 4) + ni*4 + (lm >> 2);
                    #pragma unroll
                    for (int r = 0; r < 4; r++)
                        sm.z[(rowl0 + r)*32 + ul] = v[r];
                }
            }
        }
        __syncthreads();
        float aw[9];
        #pragma unroll
        for (int i = 0; i < 9; i++) aw[i] = actw[i];
        int u0 = colBase >> 2;
        #pragma unroll
        for (int i = 0; i < TM/8; i++) {
            int idx = t + i*256;
            int row = idx >> 5, ul = idx & 31;
            int ug = u0 + ul;
            float zz = sm.z[idx];
            outH[(size_t)(rowBase + row)*outStride + ug] = __float2bfloat16(qact(zz, aw) * mask[ug]);
        }
    } else if (MODE == 5) {
        #pragma unroll
        for (int mi = 0; mi < MI; mi++) {
            int row0 = rowBase + qm + mi*16 + lq*4;
            #pragma unroll
            for (int ni = 0; ni < 4; ni++) {
                int col = colBase + qn + ni*16 + lm;
                if (col < 2048) {
                    float bb = bias[col];
                    #pragma unroll
                    for (int r = 0; r < 4; r++)
                        outH[(size_t)(row0 + r)*2048 + col] = __float2bfloat16(acc[mi][ni][r] + bb);
                } else if (col < 3072) {
                    int c = col - 2048;
                    float bb = bias2[c];
                    #pragma unroll
                    for (int r = 0; r < 4; r++)
                        outH2[(size_t)(row0 + r)*1024 + c] = __float2bfloat16(fast_tanh(acc[mi][ni][r] + bb));
                } else {
                    int c = col - 3072;
                    float bb = bias3[c];
                    #pragma unroll
                    for (int r = 0; r < 4; r++)
                        outF[(size_t)(row0 + r)*512 + c] = acc[mi][ni][r] + bb;
                }
            }
        }
    } else {  // MODE 3 (split-K partial)
        float* of = blockIdx.z ? outF2 : outF;
        #pragma unroll
        for (int mi = 0; mi < MI; mi++) {
            int row0 = rowBase + qm + mi*16 + lq*4;
            #pragma unroll
            for (int ni = 0; ni < 4; ni++) {
                int col = colBase + qn + ni*16 + lm;
                #pragma unroll
                for (int r = 0; r < 4; r++)
                    of[(size_t)(row0 + r)*outStride + col] = acc[mi][ni][r];
            }
        }
    }
}

// ---------------- in-place row softmax over 2048 cols (bf16 buffer) ----------------
__global__ __launch_bounds__(256) void k_softmax(bf16* __restrict__ ratt) {
    int b = blockIdx.x, t = threadIdx.x, w = t >> 6, lane = t & 63;
    __shared__ float red[8];
    bf16* row = ratt + (size_t)b*2048;
    float v[8];
    float mx = -1e30f;
    #pragma unroll
    for (int j = 0; j < 8; j++) {
        v[j] = __bfloat162float(row[t + j*256]);
        mx = fmaxf(mx, v[j]);
    }
    #pragma unroll
    for (int off = 32; off; off >>= 1) mx = fmaxf(mx, __shfl_xor(mx, off));
    if (lane == 0) red[w] = mx;
    __syncthreads();
    mx = fmaxf(fmaxf(red[0], red[1]), fmaxf(red[2], red[3]));
    float s = 0.f;
    #pragma unroll
    for (int j = 0; j < 8; j++) { v[j] = __expf(v[j] - mx); s += v[j]; }
    #pragma unroll
    for (int off = 32; off; off >>= 1) s += __shfl_xor(s, off);
    if (lane == 0) red[4 + w] = s;
    __syncthreads();
    float inv = 1.f / (red[4] + red[5] + red[6] + red[7]);
    #pragma unroll
    for (int j = 0; j < 8; j++)
        row[t + j*256] = __float2bfloat16(v[j] * inv);
}

// ---------------- column-mean partials ----------------
__global__ __launch_bounds__(256) void k_colpart(const bf16* __restrict__ ratt,
                                                 const bf16* __restrict__ cand,
                                                 float* __restrict__ part) {
    int ct = blockIdx.x, rc = blockIdx.y, t = threadIdx.x;
    int col = ct*256 + t;
    const bf16* src; int stride, c;
    if (ct < 8) { src = ratt; stride = 2048; c = col; }
    else        { src = cand; stride = 1024; c = col - 2048; }
    float s = 0.f;
    int r0 = rc*128;
    for (int r = 0; r < 128; r++)
        s += __bfloat162float(src[(size_t)(r0 + r)*stride + c]);
    part[rc*3072 + col] = s;
}

__global__ __launch_bounds__(256) void k_colfin(const float* __restrict__ part,
                                                const float* __restrict__ update_gate,
                                                float* __restrict__ u,
                                                float* __restrict__ cmean) {
    int col = blockIdx.x*256 + threadIdx.x;
    float s = 0.f;
    #pragma unroll
    for (int rc = 0; rc < 8; rc++) s += part[rc*3072 + col];
    s *= (1.f/1024.f);
    if (col < 2048) u[col] = s * update_gate[col];
    else            cmean[col - 2048] = s;
}

// ---------------- new_mem blend (f32 out) ----------------
__global__ __launch_bounds__(256) void k_newmem(const float* __restrict__ mem,
                                                const float* __restrict__ u,
                                                const float* __restrict__ cmean,
                                                float* __restrict__ out1) {
    int idx = blockIdx.x*256 + threadIdx.x;
    int m = idx >> 10, d = idx & 1023;
    float um = u[m];
    out1[idx] = mem[idx] * (1.f - um) + um * cmean[d];
}

// ---------------- critic: 2 rows/block, f32x4 weight loads (round-10 validated) ----------------
__global__ __launch_bounds__(256) void k_critic(
        const float* __restrict__ readv, const float* __restrict__ readv2,
        const float* __restrict__ preds, const bf16* __restrict__ hidden,
        const float* cw1, const float* cb1, const float* cw2, const float* cb2,
        const float* cw3, const float* cb3, const float* cw4, const float* cb4,
        const float* cw5, const float* cb5, const float* thr,
        float* __restrict__ out0) {
    __shared__ __align__(16) float sx[2*1024];
    __shared__ __align__(16) float sp[2*512];
    __shared__ __align__(16) short sh[2*2048];
    __shared__ __align__(16) f32x4 part[2][32][8];
    __shared__ float feat[2][96];
    __shared__ float fused[2][64];
    __shared__ float gsh[2];
    int b0 = blockIdx.x * 2, t = threadIdx.x;
    int j4 = t & 7, kg = t >> 3;

    ((f32x4*)sx)[t]       = ((const f32x4*)(readv + (size_t)b0*1024))[t]
                          + ((const f32x4*)(readv2 + (size_t)b0*1024))[t];
    ((f32x4*)sx)[t + 256] = ((const f32x4*)(readv + (size_t)b0*1024))[t + 256]
                          + ((const f32x4*)(readv2 + (size_t)b0*1024))[t + 256];
    ((f32x4*)sp)[t]       = ((const f32x4*)(preds + (size_t)b0*512))[t];
    ((s16x8*)sh)[t]       = ((const s16x8*)(hidden + (size_t)b0*2048))[t];
    ((s16x8*)sh)[t + 256] = ((const s16x8*)(hidden + (size_t)b0*2048))[t + 256];
    __syncthreads();

    {
        const f32x4* wv = (const f32x4*)cw1;
        f32x4 a0 = (f32x4){0,0,0,0}, a1 = (f32x4){0,0,0,0};
        int k0 = kg*32;
        #pragma unroll 4
        for (int k = k0; k < k0 + 32; k++) {
            f32x4 wq = wv[k*8 + j4];
            a0 += sx[k] * wq;
            a1 += sx[1024 + k] * wq;
        }
        part[0][kg][j4] = a0; part[1][kg][j4] = a1;
    }
    __syncthreads();
    if (t < 64) {
        int r = t >> 5, f = t & 31;
        float s = 0.f;
        #pragma unroll
        for (int i = 0; i < 32; i++) s += part[r][i][f >> 2][f & 3];
        feat[r][f] = fmaxf(s + cb1[f], 0.f);
    }
    __syncthreads();
    {
        const f32x4* wv = (const f32x4*)cw2;
        f32x4 a0 = (f32x4){0,0,0,0}, a1 = (f32x4){0,0,0,0};
        int k0 = kg*16;
        #pragma unroll 4
        for (int k = k0; k < k0 + 16; k++) {
            f32x4 wq = wv[k*8 + j4];
            a0 += sp[k] * wq;
            a1 += sp[512 + k] * wq;
        }
        part[0][kg][j4] = a0; part[1][kg][j4] = a1;
    }
    __syncthreads();
    if (t < 64) {
        int r = t >> 5, f = t & 31;
        float s = 0.f;
        #pragma unroll
        for (int i = 0; i < 32; i++) s += part[r][i][f >> 2][f & 3];
        feat[r][32 + f] = fmaxf(s + cb2[f], 0.f);
    }
    __syncthreads();
    {
        const f32x4* wv = (const f32x4*)cw3;
        f32x4 a0 = (f32x4){0,0,0,0}, a1 = (f32x4){0,0,0,0};
        int k0 = kg*64;
        #pragma unroll 4
        for (int k = k0; k < k0 + 64; k++) {
            f32x4 wq = wv[k*8 + j4];
            float h0 = __bfloat162float(*reinterpret_cast<const bf16*>(&sh[k]));
            float h1 = __bfloat162float(*reinterpret_cast<const bf16*>(&sh[2048 + k]));
            a0 += h0 * wq;
            a1 += h1 * wq;
        }
        part[0][kg][j4] = a0; part[1][kg][j4] = a1;
    }
    __syncthreads();
    if (t < 64) {
        int r = t >> 5, f = t & 31;
        float s = 0.f;
        #pragma unroll
        for (int i = 0; i < 32; i++) s += part[r][i][f >> 2][f & 3];
        feat[r][64 + f] = fmaxf(s + cb3[f], 0.f);
    }
    __syncthreads();
    if (t < 128) {
        int r = t >> 6, uu = t & 63;
        float s = 0.f;
        #pragma unroll 8
        for (int k = 0; k < 96; k++) s += feat[r][k] * cw4[k*64 + uu];
        fused[r][uu] = fmaxf(s + cb4[uu], 0.f);
    }
    __syncthreads();
    if (t < 128) {
        int r = t >> 6, lane = t & 63;
        float v = fused[r][lane] * cw5[lane*2];
        #pragma unroll
        for (int off = 32; off; off >>= 1) v += __shfl_xor(v, off);
        if (lane == 0)
            gsh[r] = 1.f / (1.f + __expf(-(v + cb5[0] - thr[0])));
    }
    __syncthreads();
    #pragma unroll
    for (int idx = t; idx < 1024; idx += 256) {
        int r = idx >> 9, o = idx & 511;
        out0[(size_t)(b0 + r)*512 + o] = sp[r*512 + o] * gsh[r];
    }
}

extern "C" void kernel_launch(void* const* d_in, const int* in_sizes, int n_in,
                              void* d_out, int out_size, void* d_ws, size_t ws_size,
                              hipStream_t stream) {
    const float* x        = (const float*)d_in[0];
    const float* w_       = (const float*)d_in[1];
    const float* b_bias   = (const float*)d_in[2];
    const float* gate_w   = (const float*)d_in[3];
    const float* gate_b   = (const float*)d_in[4];
    const float* act_w    = (const float*)d_in[5];
    const float* mask     = (const float*)d_in[6];
    const float* mem      = (const float*)d_in[7];
    const float* att_w    = (const float*)d_in[8];
    const float* att_b    = (const float*)d_in[9];
    const float* write_w  = (const float*)d_in[10];
    const float* write_b  = (const float*)d_in[11];
    const float* upd_gate = (const float*)d_in[12];
    const float* out_w    = (const float*)d_in[13];
    const float* out_b    = (const float*)d_in[14];
    const float* cw1 = (const float*)d_in[15]; const float* cb1 = (const float*)d_in[16];
    const float* cw2 = (const float*)d_in[17]; const float* cb2 = (const float*)d_in[18];
    const float* cw3 = (const float*)d_in[19]; const float* cb3 = (const float*)d_in[20];
    const float* cw4 = (const float*)d_in[21]; const float* cb4 = (const float*)d_in[22];
    const float* cw5 = (const float*)d_in[23]; const float* cb5 = (const float*)d_in[24];
    const float* thr = (const float*)d_in[25];

    char* ws = (char*)d_ws;
    float* gate   = (float*)(ws + GATE_OFF);
    float* actw   = (float*)(ws + ACTW_OFF);
    float* uvec   = (float*)(ws + U_OFF);
    float* cmean  = (float*)(ws + CMEAN_OFF);
    float* part   = (float*)(ws + PART_OFF);
    bf16*  hidden = (bf16*)(ws + HIDDEN_OFF);
    bf16*  ratt   = (bf16*)(ws + RATT_OFF);
    bf16*  cand   = (bf16*)(ws + CAND_OFF);
    float* preds  = (float*)(ws + PREDS_OFF);
    float* readv  = (float*)(ws + READ_OFF);
    float* readv2 = (float*)(ws + READ2_OFF);   // aliases wT head (dead after G1)
    bf16*  xbf    = (bf16*)(ws + XBF_OFF);
    bf16*  wT     = (bf16*)(ws + WT_OFF);
    bf16*  catT   = (bf16*)(ws + CATT_OFF);
    bf16*  memT   = (bf16*)(ws + MEMT_OFF);

    float* out0 = (float*)d_out;            // (1024, 512)
    float* out1 = out0 + 1024*512;          // (2048, 1024)

    // fused prepass: cvt + gate + all 5 transposes (6400 blocks, one dispatch)
    k_prepass<<<6400, 256, 0, stream>>>(x, xbf, gate_w, gate_b, act_w, gate, actw,
        w_, wT, att_w, write_w, out_w, catT, mem, memT);

    // G1: hidden = qact((x@w + b)·gate) * mask     [M=1024, N=8192, K=1024] — 1024 blocks
    gemm_bt<4, 64><<<dim3(64, 16), 256, 0, stream>>>(xbf, wT, 1024, 1024, 1024, 0,
        b_bias, nullptr, nullptr, nullptr, nullptr, hidden, nullptr, gate, actw, mask, 2048);
    // G234 fused: [att|write|out] heads            [M=1024, N=3584, K=2048] — 448 blocks
    gemm_bt<5, 64><<<dim3(28, 16), 256, 0, stream>>>(hidden, catT, 2048, 2048, 2048, 0,
        att_b, write_b, out_b, preds, nullptr, ratt, cand, nullptr, nullptr, nullptr, 0);
    k_softmax<<<1024, 256, 0, stream>>>(ratt);
    // G5: read = ratt @ mem, split-K=2             [M=1024, N=1024, K=2x1024] — 256 blocks
    gemm_bt<3, 64><<<dim3(8, 16, 2), 256, 0, stream>>>(ratt, memT, 1024, 2048, 2048, 1024,
        nullptr, nullptr, nullptr, readv, readv2, nullptr, nullptr, nullptr, nullptr, nullptr, 1024);

    k_colpart<<<dim3(12, 8), 256, 0, stream>>>(ratt, cand, part);
    k_colfin<<<12, 256, 0, stream>>>(part, upd_gate, uvec, cmean);
    k_newmem<<<8192, 256, 0, stream>>>(mem, uvec, cmean, out1);
    k_critic<<<512, 256, 0, stream>>>(readv, readv2, preds, hidden,
        cw1, cb1, cw2, cb2, cw3, cb3, cw4, cb4, cw5, cb5, thr, out0);
}